// Round 11
// baseline (1219.858 us; speedup 1.0000x reference)
//
#include <hip/hip_runtime.h>
#include <hip/hip_fp16.h>
#include <cstddef>

#define EPSV 1e-5f
#define SPLITS 4

typedef _Float16 f16;
typedef _Float16 f16x8 __attribute__((ext_vector_type(8)));
typedef float f32x4v __attribute__((ext_vector_type(4)));

__device__ __forceinline__ float gelu_f(float x) {
    return 0.5f * x * (1.0f + erff(x * 0.7071067811865476f));
}

// branch-free tanh-GELU: x*(1 - 1/(exp2(z)+1)), z = x*(2.3025851+0.10296103 x^2)
__device__ __forceinline__ float gelu_fast(float x) {
    float x2 = x * x;
    float z = x * fmaf(0.10296103f, x2, 2.3025851f);
    float e = exp2f(z);
    float r = __builtin_amdgcn_rcpf(e + 1.0f);
    return fmaf(-x, r, x);
}

// ---------------- all-weights f32 -> f16 convert (one dispatch) ----------------
__global__ __launch_bounds__(256) void cvt_all_kernel(
    const float* __restrict__ p0, const float* __restrict__ p1,
    const float* __restrict__ p2, const float* __restrict__ p3,
    const float* __restrict__ p4, const float* __restrict__ p5,
    f16* __restrict__ dst)
{
    const int n = 10960896;
    for (int i = blockIdx.x * 256 + threadIdx.x; i < n; i += gridDim.x * 256) {
        const float* s; int off;
        if      (i <   49152) { s = p0; off = i; }
        else if (i <  344064) { s = p1; off = i -   49152; }
        else if (i < 2998272) { s = p2; off = i -  344064; }
        else if (i < 3883008) { s = p3; off = i - 2998272; }
        else if (i < 7421952) { s = p4; off = i - 3883008; }
        else                  { s = p5; off = i - 7421952; }
        dst[i] = (f16)s[off];
    }
}

// ---------------- conv weight reorder ----------------
__global__ __launch_bounds__(256) void conv_w_reorder_kernel(
    const float* __restrict__ w, f16* __restrict__ out, int CO, int CI)
{
    int n = CO * CI * 9;
    for (int i = blockIdx.x * 256 + threadIdx.x; i < n; i += gridDim.x * 256) {
        int t = i % 9; int r = i / 9;
        int ci = r % CI; int co = r / CI;
        out[(size_t)co * CI * 9 + t * CI + ci] = (f16)w[i];
    }
}

// ---------------- conv1 weight prep ----------------
__global__ __launch_bounds__(256) void conv1_w_prep_kernel(
    const float* __restrict__ w, const float* __restrict__ g,
    const float* __restrict__ vr, f16* __restrict__ wB)
{
    int i = blockIdx.x * 256 + threadIdx.x;
    if (i >= 1024) return;
    int co = i >> 5, k = i & 31;
    float inv = g[co] * rsqrtf(vr[co] + EPSV);
    wB[i] = (f16)((k < 25) ? w[co * 25 + k] * inv : 0.f);
}

// ---------------- conv1: 5x5 s2 p2 via MFMA implicit GEMM, NHWC f16 ----------------
__global__ __launch_bounds__(256) void conv1_mfma_kernel(
    const float* __restrict__ in, const f16* __restrict__ wB,
    const float* __restrict__ bt, const float* __restrict__ mn,
    const float* __restrict__ g, const float* __restrict__ vr,
    f16* __restrict__ out)
{
    __shared__ __align__(16) f16 inpH[35 * 36 + 8];
    __shared__ __align__(16) f16 Bs[32 * 32];
    int bid = blockIdx.x;
    int n = bid >> 4; int tile = bid & 15;
    int ty0 = (tile >> 2) * 16, tx0 = (tile & 3) * 16;
    int t = threadIdx.x;
    const float* ip = in + (size_t)n * 16384;
    for (int e = t; e < 35 * 36; e += 256) {
        int r = e / 36, c = e - r * 36;
        int iy = ty0 * 2 - 2 + r, ix = tx0 * 2 - 2 + c;
        float v = ((unsigned)iy < 128u && (unsigned)ix < 128u && c < 35) ? ip[iy * 128 + ix] : 0.f;
        inpH[e] = (f16)v;
    }
    if (t < 128) {
        int row = t >> 2, seg = (t & 3) * 8;
        *(uint4*)(&Bs[row * 32 + seg]) = *(const uint4*)(wB + row * 32 + seg);
    }
    __syncthreads();
    int w = t >> 6, lane = t & 63;
    int l15 = lane & 15, gq = lane >> 4;
    f16x8 afr[4];
    #pragma unroll
    for (int i = 0; i < 4; i++) {
        int mt = 4 * w + i;
        f16 tmp[8];
        #pragma unroll
        for (int e = 0; e < 8; e++) {
            int kk = 8 * gq + e; if (kk > 24) kk = 24;
            int ky = kk / 5, kx = kk - ky * 5;
            tmp[e] = inpH[(2 * mt + ky) * 36 + 2 * l15 + kx];
        }
        afr[i] = *(f16x8*)tmp;
    }
    f16x8 bfr[2];
    bfr[0] = *(const f16x8*)(&Bs[l15 * 32 + 8 * gq]);
    bfr[1] = *(const f16x8*)(&Bs[(16 + l15) * 32 + 8 * gq]);
    f32x4v zero = {0.f, 0.f, 0.f, 0.f};
    f32x4v acc[4][2];
    #pragma unroll
    for (int i = 0; i < 4; i++) { acc[i][0] = zero; acc[i][1] = zero; }
    #pragma unroll
    for (int i = 0; i < 4; i++) {
        acc[i][0] = __builtin_amdgcn_mfma_f32_16x16x32_f16(afr[i], bfr[0], acc[i][0], 0, 0, 0);
        acc[i][1] = __builtin_amdgcn_mfma_f32_16x16x32_f16(afr[i], bfr[1], acc[i][1], 0, 0, 0);
    }
    float beta[2];
    #pragma unroll
    for (int nt = 0; nt < 2; nt++) {
        int co = nt * 16 + l15;
        float inv = g[co] * rsqrtf(vr[co] + EPSV);
        beta[nt] = bt[co] - mn[co] * inv;
    }
    #pragma unroll
    for (int i = 0; i < 4; i++) {
        int y = ty0 + 4 * w + i;
        #pragma unroll
        for (int q = 0; q < 4; q++) {
            int x = tx0 + 4 * gq + q;
            size_t ob = (((size_t)n * 64 + y) * 64 + x) * 32;
            #pragma unroll
            for (int nt = 0; nt < 2; nt++) {
                int co = nt * 16 + l15;
                out[ob + co] = (f16)gelu_fast(acc[i][nt][q] + beta[nt]);
            }
        }
    }
}

// ---------------- implicit-GEMM conv 3x3 s2 p1, NHWC f16, MFMA, reg prefetch ----------------
template<int CI, int HI, int CO>
__global__ __launch_bounds__(256) void convg_kernel(
    const f16* __restrict__ in, const f16* __restrict__ wr_,
    const float* __restrict__ g, const float* __restrict__ bt,
    const float* __restrict__ mn, const float* __restrict__ vr,
    f16* __restrict__ out)
{
    constexpr int HO = HI / 2;
    constexpr int HOB = (HO == 32) ? 5 : 4;
    constexpr int K = 9 * CI;
    __shared__ __align__(16) f16 As[64 * 40];
    __shared__ __align__(16) f16 Bs[64 * 40];
    int tid = threadIdx.x;
    int bm = blockIdx.x * 64;
    int bn = blockIdx.y * 64;
    int lrow = tid >> 2, lseg = tid & 3;
    int w = tid >> 6, lane = tid & 63;
    int wr = (w >> 1) * 32, wc = (w & 1) * 32;
    int l15 = lane & 15, l4 = lane >> 4;
    int gp = bm + lrow;
    int pn = gp >> (2 * HOB);
    int prem = gp & ((1 << (2 * HOB)) - 1);
    int oy = prem >> HOB, ox = prem & (HO - 1);

    f32x4v zero = {0.f, 0.f, 0.f, 0.f};
    f32x4v acc[2][2];
    acc[0][0] = zero; acc[0][1] = zero; acc[1][0] = zero; acc[1][1] = zero;

    auto loadTile = [&](int k0, uint4& av, uint4& bv) {
        int tap = k0 / CI;
        int cio = k0 - tap * CI;
        int ky = tap / 3, kx = tap - ky * 3;
        int iy = oy * 2 - 1 + ky, ix = ox * 2 - 1 + kx;
        av = make_uint4(0u, 0u, 0u, 0u);
        if ((unsigned)iy < (unsigned)HI && (unsigned)ix < (unsigned)HI)
            av = *(const uint4*)(in + (((size_t)(pn * HI + iy)) * HI + ix) * CI + cio + lseg * 8);
        bv = *(const uint4*)(wr_ + (size_t)(bn + lrow) * K + k0 + lseg * 8);
    };

    uint4 ra, rb;
    loadTile(0, ra, rb);
    for (int k0 = 0; k0 < K; k0 += 32) {
        __syncthreads();
        *(uint4*)(&As[lrow * 40 + lseg * 8]) = ra;
        *(uint4*)(&Bs[lrow * 40 + lseg * 8]) = rb;
        if (k0 + 32 < K) loadTile(k0 + 32, ra, rb);
        __syncthreads();
        f16x8 a0 = *(const f16x8*)(&As[(wr + l15) * 40 + l4 * 8]);
        f16x8 a1 = *(const f16x8*)(&As[(wr + 16 + l15) * 40 + l4 * 8]);
        f16x8 b0 = *(const f16x8*)(&Bs[(wc + l15) * 40 + l4 * 8]);
        f16x8 b1 = *(const f16x8*)(&Bs[(wc + 16 + l15) * 40 + l4 * 8]);
        acc[0][0] = __builtin_amdgcn_mfma_f32_16x16x32_f16(a0, b0, acc[0][0], 0, 0, 0);
        acc[0][1] = __builtin_amdgcn_mfma_f32_16x16x32_f16(a0, b1, acc[0][1], 0, 0, 0);
        acc[1][0] = __builtin_amdgcn_mfma_f32_16x16x32_f16(a1, b0, acc[1][0], 0, 0, 0);
        acc[1][1] = __builtin_amdgcn_mfma_f32_16x16x32_f16(a1, b1, acc[1][1], 0, 0, 0);
    }
    float inv[2], beta[2];
    #pragma unroll
    for (int ni = 0; ni < 2; ni++) {
        int col = bn + wc + ni * 16 + l15;
        float iv = g[col] * rsqrtf(vr[col] + EPSV);
        inv[ni] = iv; beta[ni] = bt[col] - mn[col] * iv;
    }
    #pragma unroll
    for (int mi = 0; mi < 2; mi++) {
        #pragma unroll
        for (int q = 0; q < 4; q++) {
            int pixel = bm + wr + mi * 16 + l4 * 4 + q;
            #pragma unroll
            for (int ni = 0; ni < 2; ni++) {
                int col = bn + wc + ni * 16 + l15;
                float v = acc[mi][ni][q] * inv[ni] + beta[ni];
                out[(size_t)pixel * CO + col] = (f16)gelu_fast(v);
            }
        }
    }
}

// ---------------- 4x4 avg pool NHWC f16 ----------------
__global__ __launch_bounds__(256) void poolh_kernel(
    const f16* __restrict__ in, f16* __restrict__ out, int NC)
{
    int idx = blockIdx.x * 256 + threadIdx.x;
    if (idx >= NC * 16 * 16) return;
    int cc = idx & 15; int npl = idx >> 4;
    int c0 = cc * 8;
    int n = npl >> 4; int p = npl & 15;
    int ph = p >> 2, pw = p & 3;
    const f16* base = in + (((size_t)(n * 16 + ph * 4)) * 16 + pw * 4) * 128 + c0;
    float s[8] = {};
    #pragma unroll
    for (int dy = 0; dy < 4; dy++)
        #pragma unroll
        for (int dx = 0; dx < 4; dx++) {
            f16x8 v = *(const f16x8*)(base + (dy * 16 + dx) * 128);
            #pragma unroll
            for (int u = 0; u < 8; u++) s[u] += (float)v[u];
        }
    f16* op = out + (size_t)npl * 128 + c0;
    #pragma unroll
    for (int u = 0; u < 8; u++) op[u] = (f16)(s[u] * 0.0625f);
}

// ---------------- MFMA f16 NT GEMM, 64x64 tile, BK=64, XCD-swizzled 1D grid ----------------
template<int OUTF16, int ACT, int TCMAP>
__global__ __launch_bounds__(256) void gemm_k64_kernel(
    const f16* __restrict__ A, const f16* __restrict__ B,
    const float* __restrict__ bias, const float* __restrict__ res,
    void* __restrict__ Cv, int M, int N, int K, int nrow)
{
    __shared__ __align__(16) f16 As[64 * 72];
    __shared__ __align__(16) f16 Bs[64 * 72];
    int nb = gridDim.x;
    int q = nb >> 3, r = nb & 7;
    int xcd = blockIdx.x & 7, pos = blockIdx.x >> 3;
    int logical = (xcd < r ? xcd * (q + 1) : r * (q + 1) + (xcd - r) * q) + pos;
    int brow = logical % nrow, bcol = logical / nrow;
    int bm = brow * 64, bn = bcol * 64;

    int tid = threadIdx.x;
    int lrow = tid >> 2, lseg = (tid & 3) * 16;
    int w = tid >> 6, lane = tid & 63;
    int wr = (w >> 1) * 32, wc = (w & 1) * 32;
    int l15 = lane & 15, l4 = lane >> 4;
    f32x4v zero = {0.f, 0.f, 0.f, 0.f};
    f32x4v acc[2][2];
    acc[0][0] = zero; acc[0][1] = zero; acc[1][0] = zero; acc[1][1] = zero;

    int arow = bm + lrow;
    bool aok = (arow < M);
    const f16* ap = A + (size_t)arow * K + lseg;
    const f16* bp = B + (size_t)(bn + lrow) * K + lseg;

    uint4 ra0 = make_uint4(0u,0u,0u,0u), ra1 = ra0, rb0, rb1;
    if (aok) { ra0 = *(const uint4*)(ap); ra1 = *(const uint4*)(ap + 8); }
    rb0 = *(const uint4*)(bp); rb1 = *(const uint4*)(bp + 8);

    int nt = K >> 6;
    for (int t = 0; t < nt; t++) {
        __syncthreads();
        *(uint4*)(&As[lrow * 72 + lseg])     = ra0;
        *(uint4*)(&As[lrow * 72 + lseg + 8]) = ra1;
        *(uint4*)(&Bs[lrow * 72 + lseg])     = rb0;
        *(uint4*)(&Bs[lrow * 72 + lseg + 8]) = rb1;
        if (t + 1 < nt) {
            int k0 = (t + 1) << 6;
            if (aok) { ra0 = *(const uint4*)(ap + k0); ra1 = *(const uint4*)(ap + k0 + 8); }
            rb0 = *(const uint4*)(bp + k0); rb1 = *(const uint4*)(bp + k0 + 8);
        }
        __syncthreads();
        #pragma unroll
        for (int s = 0; s < 2; s++) {
            f16x8 a0 = *(const f16x8*)(&As[(wr + l15) * 72 + s * 32 + l4 * 8]);
            f16x8 a1 = *(const f16x8*)(&As[(wr + 16 + l15) * 72 + s * 32 + l4 * 8]);
            f16x8 b0 = *(const f16x8*)(&Bs[(wc + l15) * 72 + s * 32 + l4 * 8]);
            f16x8 b1 = *(const f16x8*)(&Bs[(wc + 16 + l15) * 72 + s * 32 + l4 * 8]);
            acc[0][0] = __builtin_amdgcn_mfma_f32_16x16x32_f16(a0, b0, acc[0][0], 0, 0, 0);
            acc[0][1] = __builtin_amdgcn_mfma_f32_16x16x32_f16(a0, b1, acc[0][1], 0, 0, 0);
            acc[1][0] = __builtin_amdgcn_mfma_f32_16x16x32_f16(a1, b0, acc[1][0], 0, 0, 0);
            acc[1][1] = __builtin_amdgcn_mfma_f32_16x16x32_f16(a1, b1, acc[1][1], 0, 0, 0);
        }
    }

    #pragma unroll
    for (int mi = 0; mi < 2; mi++) {
        #pragma unroll
        for (int qq = 0; qq < 4; qq++) {
            int row = bm + wr + mi * 16 + l4 * 4 + qq;
            if (row >= M) continue;
            #pragma unroll
            for (int ni = 0; ni < 2; ni++) {
                int col = bn + wc + ni * 16 + l15;
                float v = acc[mi][ni][qq];
                if (bias) v += bias[col];
                if (ACT == 1) v = gelu_fast(v);
                if (res) v += res[(size_t)row * N + col];
                int orow = row;
                if (TCMAP) orow = (row & ~511) | ((row & 15) << 5) | ((row >> 4) & 31);
                if (OUTF16) ((f16*)Cv)[(size_t)orow * N + col] = (f16)v;
                else ((float*)Cv)[(size_t)orow * N + col] = v;
            }
        }
    }
}

// ---------------- fused-LN MFMA GEMM: C = act(LN(Xf32) @ B^T + bias), K=384 fixed ----------------
// A fully resident in LDS [64][392]; B streamed in 6 chunks of 64 with reg prefetch.
// VTRANS: column blocks bn>=768 write transposed V into vT.
template<int ACT, int VTRANS>
__global__ __launch_bounds__(256) void gemm_ln_kernel(
    const float* __restrict__ Xf, const float* __restrict__ lng, const float* __restrict__ lnb,
    const f16* __restrict__ B, const float* __restrict__ bias,
    f16* __restrict__ C, f16* __restrict__ vT, int M, int N, int nrow)
{
    __shared__ __align__(16) f16 As[64 * 392];
    __shared__ __align__(16) f16 Bs[64 * 72];
    int nb = gridDim.x;
    int q = nb >> 3, r = nb & 7;
    int xcd = blockIdx.x & 7, pos = blockIdx.x >> 3;
    int logical = (xcd < r ? xcd * (q + 1) : r * (q + 1) + (xcd - r) * q) + pos;
    int brow = logical % nrow, bcol = logical / nrow;
    int bm = brow * 64, bn = bcol * 64;

    int tid = threadIdx.x;
    int lrow = tid >> 2, g = tid & 3;
    int lseg = g * 16;
    int w = tid >> 6, lane = tid & 63;
    int wr = (w >> 1) * 32, wc = (w & 1) * 32;
    int l15 = lane & 15, l4 = lane >> 4;

    // ---- A: two-pass load + LN into LDS ----
    int arow = bm + lrow;
    bool aok = (arow < M);
    const float* xp = Xf + (size_t)arow * 384;
    float s = 0.f, s2 = 0.f;
    if (aok) {
        #pragma unroll
        for (int k = 0; k < 6; k++)
            #pragma unroll
            for (int j = 0; j < 4; j++) {
                float4 v = *(const float4*)(xp + k * 64 + lseg + j * 4);
                s += v.x + v.y + v.z + v.w;
                s2 += v.x * v.x + v.y * v.y + v.z * v.z + v.w * v.w;
            }
    }
    s += __shfl_xor(s, 1); s += __shfl_xor(s, 2);
    s2 += __shfl_xor(s2, 1); s2 += __shfl_xor(s2, 2);
    float mu = s * (1.f / 384.f);
    float var = s2 * (1.f / 384.f) - mu * mu;
    float rs = rsqrtf(var + EPSV);
    #pragma unroll
    for (int k = 0; k < 6; k++) {
        f16 tmp[16];
        #pragma unroll
        for (int j = 0; j < 4; j++) {
            int c = k * 64 + lseg + j * 4;
            float4 v = aok ? *(const float4*)(xp + c) : make_float4(0.f, 0.f, 0.f, 0.f);
            float4 gg = *(const float4*)(lng + c);
            float4 bb = *(const float4*)(lnb + c);
            tmp[j * 4 + 0] = (f16)((v.x - mu) * rs * gg.x + bb.x);
            tmp[j * 4 + 1] = (f16)((v.y - mu) * rs * gg.y + bb.y);
            tmp[j * 4 + 2] = (f16)((v.z - mu) * rs * gg.z + bb.z);
            tmp[j * 4 + 3] = (f16)((v.w - mu) * rs * gg.w + bb.w);
        }
        *(uint4*)(&As[lrow * 392 + k * 64 + lseg])     = *(uint4*)(tmp);
        *(uint4*)(&As[lrow * 392 + k * 64 + lseg + 8]) = *(uint4*)(tmp + 8);
    }

    // ---- B streaming + MFMA ----
    const f16* bp = B + (size_t)(bn + lrow) * 384 + lseg;
    uint4 rb0 = *(const uint4*)(bp), rb1 = *(const uint4*)(bp + 8);
    __syncthreads();   // As ready

    f32x4v zero = {0.f, 0.f, 0.f, 0.f};
    f32x4v acc[2][2];
    acc[0][0] = zero; acc[0][1] = zero; acc[1][0] = zero; acc[1][1] = zero;

    for (int t = 0; t < 6; t++) {
        *(uint4*)(&Bs[lrow * 72 + lseg])     = rb0;
        *(uint4*)(&Bs[lrow * 72 + lseg + 8]) = rb1;
        if (t < 5) {
            rb0 = *(const uint4*)(bp + (t + 1) * 64);
            rb1 = *(const uint4*)(bp + (t + 1) * 64 + 8);
        }
        __syncthreads();
        #pragma unroll
        for (int ss = 0; ss < 2; ss++) {
            f16x8 a0 = *(const f16x8*)(&As[(wr + l15) * 392 + t * 64 + ss * 32 + l4 * 8]);
            f16x8 a1 = *(const f16x8*)(&As[(wr + 16 + l15) * 392 + t * 64 + ss * 32 + l4 * 8]);
            f16x8 b0 = *(const f16x8*)(&Bs[(wc + l15) * 72 + ss * 32 + l4 * 8]);
            f16x8 b1 = *(const f16x8*)(&Bs[(wc + 16 + l15) * 72 + ss * 32 + l4 * 8]);
            acc[0][0] = __builtin_amdgcn_mfma_f32_16x16x32_f16(a0, b0, acc[0][0], 0, 0, 0);
            acc[0][1] = __builtin_amdgcn_mfma_f32_16x16x32_f16(a0, b1, acc[0][1], 0, 0, 0);
            acc[1][0] = __builtin_amdgcn_mfma_f32_16x16x32_f16(a1, b0, acc[1][0], 0, 0, 0);
            acc[1][1] = __builtin_amdgcn_mfma_f32_16x16x32_f16(a1, b1, acc[1][1], 0, 0, 0);
        }
        __syncthreads();
    }

    if (VTRANS && bn >= 768) {
        f16* tile = As;   // [64][66]
        #pragma unroll
        for (int mi = 0; mi < 2; mi++)
            #pragma unroll
            for (int qq = 0; qq < 4; qq++) {
                int rl = wr + mi * 16 + l4 * 4 + qq;
                #pragma unroll
                for (int ni = 0; ni < 2; ni++) {
                    int dl = wc + ni * 16 + l15;
                    float v = acc[mi][ni][qq] + bias[bn + dl];
                    tile[dl * 66 + rl] = (f16)v;
                }
            }
        __syncthreads();
        int h = (bn - 768) >> 6;
        int j = tid & 63, dbase = tid >> 6;
        int trow = bm + j;
        if (trow < M) {
            int b = trow / 513;
            int jj = trow - b * 513;
            f16* vb = vT + ((size_t)(b * 6 + h) * 64) * 576 + jj;
            #pragma unroll
            for (int it = 0; it < 16; it++) {
                int d = dbase * 16 + it;
                vb[(size_t)d * 576] = tile[d * 66 + j];
            }
        }
        return;
    }
    #pragma unroll
    for (int mi = 0; mi < 2; mi++) {
        #pragma unroll
        for (int qq = 0; qq < 4; qq++) {
            int row = bm + wr + mi * 16 + l4 * 4 + qq;
            if (row >= M) continue;
            #pragma unroll
            for (int ni = 0; ni < 2; ni++) {
                int col = bn + wc + ni * 16 + l15;
                float v = acc[mi][ni][qq] + bias[col];
                if (ACT == 1) v = gelu_fast(v);
                C[(size_t)row * N + col] = (f16)v;
            }
        }
    }
}

// ---------------- out-proj GEMM with fused attention-partial combine ----------------
// A[row][h*64+d] = sum_s Op[s][(b*6+h)*513+qi][d] * scale_h[s]; C = A@B^T + bias + xio (f32, in-place)
__global__ __launch_bounds__(256) void gemm_comb_kernel(
    const f16* __restrict__ Op, const float* __restrict__ ml,
    const f16* __restrict__ B, const float* __restrict__ bias,
    float* __restrict__ xio, int M, int nrow)
{
    __shared__ __align__(16) f16 As[64 * 392];
    __shared__ __align__(16) f16 Bs[64 * 72];
    int nb = gridDim.x;
    int q = nb >> 3, r = nb & 7;
    int xcd = blockIdx.x & 7, pos = blockIdx.x >> 3;
    int logical = (xcd < r ? xcd * (q + 1) : r * (q + 1) + (xcd - r) * q) + pos;
    int brow = logical % nrow, bcol = logical / nrow;
    int bm = brow * 64, bn = bcol * 64;

    int tid = threadIdx.x;
    int lrow = tid >> 2, g = tid & 3;
    int lseg = g * 16;
    int w = tid >> 6, lane = tid & 63;
    int wr = (w >> 1) * 32, wc = (w & 1) * 32;
    int l15 = lane & 15, l4 = lane >> 4;

    // ---- A: combine SPLITS partials per head-chunk into LDS ----
    int arow = bm + lrow;
    bool aok = (arow < M);
    int b = aok ? arow / 513 : 0;
    int qi = arow - b * 513;
    #pragma unroll
    for (int h = 0; h < 6; h++) {
        f16 tmp[16];
        if (aok) {
            size_t oprow = (size_t)(b * 6 + h) * 513 + qi;
            float mv[SPLITS], lv[SPLITS], mm = -INFINITY;
            #pragma unroll
            for (int sp = 0; sp < SPLITS; sp++) {
                mv[sp] = ml[((size_t)sp * 24624 + oprow) * 2];
                lv[sp] = ml[((size_t)sp * 24624 + oprow) * 2 + 1];
                mm = fmaxf(mm, mv[sp]);
            }
            float sc[SPLITS], lden = 0.f;
            #pragma unroll
            for (int sp = 0; sp < SPLITS; sp++) {
                float a = (mv[sp] == -INFINITY) ? 0.f : __expf(mv[sp] - mm);
                sc[sp] = a; lden += lv[sp] * a;
            }
            float rl = 1.0f / lden;
            float accv[16] = {};
            #pragma unroll
            for (int sp = 0; sp < SPLITS; sp++) {
                f16x8 o0 = *(const f16x8*)(Op + ((size_t)sp * 24624 + oprow) * 64 + lseg);
                f16x8 o1 = *(const f16x8*)(Op + ((size_t)sp * 24624 + oprow) * 64 + lseg + 8);
                #pragma unroll
                for (int e = 0; e < 8; e++) {
                    accv[e]     = fmaf((float)o0[e], sc[sp], accv[e]);
                    accv[e + 8] = fmaf((float)o1[e], sc[sp], accv[e + 8]);
                }
            }
            #pragma unroll
            for (int e = 0; e < 16; e++) tmp[e] = (f16)(accv[e] * rl);
        } else {
            #pragma unroll
            for (int e = 0; e < 16; e++) tmp[e] = (f16)0.f;
        }
        *(uint4*)(&As[lrow * 392 + h * 64 + lseg])     = *(uint4*)(tmp);
        *(uint4*)(&As[lrow * 392 + h * 64 + lseg + 8]) = *(uint4*)(tmp + 8);
    }

    const f16* bp = B + (size_t)(bn + lrow) * 384 + lseg;
    uint4 rb0 = *(const uint4*)(bp), rb1 = *(const uint4*)(bp + 8);
    __syncthreads();

    f32x4v zero = {0.f, 0.f, 0.f, 0.f};
    f32x4v acc[2][2];
    acc[0][0] = zero; acc[0][1] = zero; acc[1][0] = zero; acc[1][1] = zero;

    for (int t = 0; t < 6; t++) {
        *(uint4*)(&Bs[lrow * 72 + lseg])     = rb0;
        *(uint4*)(&Bs[lrow * 72 + lseg + 8]) = rb1;
        if (t < 5) {
            rb0 = *(const uint4*)(bp + (t + 1) * 64);
            rb1 = *(const uint4*)(bp + (t + 1) * 64 + 8);
        }
        __syncthreads();
        #pragma unroll
        for (int ss = 0; ss < 2; ss++) {
            f16x8 a0 = *(const f16x8*)(&As[(wr + l15) * 392 + t * 64 + ss * 32 + l4 * 8]);
            f16x8 a1 = *(const f16x8*)(&As[(wr + 16 + l15) * 392 + t * 64 + ss * 32 + l4 * 8]);
            f16x8 b0 = *(const f16x8*)(&Bs[(wc + l15) * 72 + ss * 32 + l4 * 8]);
            f16x8 b1 = *(const f16x8*)(&Bs[(wc + 16 + l15) * 72 + ss * 32 + l4 * 8]);
            acc[0][0] = __builtin_amdgcn_mfma_f32_16x16x32_f16(a0, b0, acc[0][0], 0, 0, 0);
            acc[0][1] = __builtin_amdgcn_mfma_f32_16x16x32_f16(a0, b1, acc[0][1], 0, 0, 0);
            acc[1][0] = __builtin_amdgcn_mfma_f32_16x16x32_f16(a1, b0, acc[1][0], 0, 0, 0);
            acc[1][1] = __builtin_amdgcn_mfma_f32_16x16x32_f16(a1, b1, acc[1][1], 0, 0, 0);
        }
        __syncthreads();
    }

    #pragma unroll
    for (int mi = 0; mi < 2; mi++) {
        #pragma unroll
        for (int qq = 0; qq < 4; qq++) {
            int row = bm + wr + mi * 16 + l4 * 4 + qq;
            if (row >= M) continue;
            #pragma unroll
            for (int ni = 0; ni < 2; ni++) {
                int col = bn + wc + ni * 16 + l15;
                float v = acc[mi][ni][qq] + bias[col];
                v += xio[(size_t)row * 384 + col];
                xio[(size_t)row * 384 + col] = v;
            }
        }
    }
}

// ---------------- depthwise temporal conv + bias + gelu -> f16 ----------------
__global__ __launch_bounds__(256) void dwconv_kernel(
    const float* __restrict__ in, const float* __restrict__ w,
    const float* __restrict__ bias, f16* __restrict__ out, int dil)
{
    int idx = blockIdx.x * 256 + threadIdx.x;
    if (idx >= 128 * 32 * 384) return;
    int d = idx % 384; int t = (idx / 384) & 31; int s = idx / (384 * 32);
    const float* ip = in + (size_t)s * 32 * 384 + d;
    float acc = bias[d];
    #pragma unroll
    for (int k = 0; k < 3; k++) {
        int tt = t + (k - 1) * dil;
        if ((unsigned)tt < 32u) acc += w[d * 3 + k] * ip[tt * 384];
    }
    out[idx] = (f16)gelu_fast(acc);
}

// ---------------- mixer-final LN + positional add ----------------
__global__ __launch_bounds__(128) void build_x_kernel(
    const float* __restrict__ mix, const float* __restrict__ tc,
    const float* __restrict__ tg, const float* __restrict__ tb,
    const float* __restrict__ fpos, const float* __restrict__ ppos,
    float* __restrict__ x)
{
    int row = blockIdx.x;
    int t = row & 31; int bp = row >> 5;
    int p = bp & 15; int b = bp >> 4;
    int tid = threadIdx.x;
    const float* ip = mix + (size_t)row * 384;
    const float* ip2 = tc + (size_t)row * 384;
    __shared__ float red[128], red2[128];
    float v[3]; float s = 0.f, s2 = 0.f;
    #pragma unroll
    for (int j = 0; j < 3; j++) {
        float val = ip[tid + 128 * j] + ip2[tid + 128 * j];
        v[j] = val; s += val; s2 += val * val;
    }
    red[tid] = s; red2[tid] = s2; __syncthreads();
    for (int off = 64; off >= 1; off >>= 1) {
        if (tid < off) { red[tid] += red[tid + off]; red2[tid] += red2[tid + off]; }
        __syncthreads();
    }
    float mu = red[0] * (1.f / 384.f);
    float var = red2[0] * (1.f / 384.f) - mu * mu;
    float rs = rsqrtf(var + EPSV);
    size_t xbase = ((size_t)b * 513 + 1 + t * 16 + p) * 384;
    #pragma unroll
    for (int j = 0; j < 3; j++) {
        int c = tid + 128 * j;
        float y = (v[j] - mu) * rs * tg[c] + tb[c] + fpos[t * 384 + c] + ppos[p * 384 + c];
        x[xbase + c] = y;
    }
}

__global__ __launch_bounds__(256) void cls_kernel(
    const float* __restrict__ ct, const float* __restrict__ cp, float* __restrict__ x)
{
    int idx = blockIdx.x * 256 + threadIdx.x;
    if (idx >= 8 * 384) return;
    int c = idx % 384; int b = idx / 384;
    x[(size_t)b * 513 * 384 + c] = ct[c] + cp[c];
}

// ---------------- flash attention, SPLITS-way j-split + K/V register prefetch ----------------
__global__ __launch_bounds__(256) void fattn_split_kernel(
    const f16* __restrict__ qkv, const f16* __restrict__ vT,
    f16* __restrict__ Op, float* __restrict__ ml)
{
    __shared__ __align__(16) f16 Pl[4][16][72];
    int qt = blockIdx.x;
    int bh = blockIdx.y; int h = bh % 6; int b = bh / 6;
    int third = blockIdx.z;
    int tid = threadIdx.x;
    int w = tid >> 6, lane = tid & 63;
    int l15 = lane & 15, g = lane >> 4;
    int q0w = qt * 64 + w * 16;
    if (q0w > 512) return;
    const size_t RS = 1152;
    const f16* qbase = qkv + (size_t)b * 513 * RS + h * 64;
    const f16* kbase = qbase + 384;
    const f16* vtb = vT + (size_t)bh * 64 * 576;

    f16x8 qf[2];
    {
        int qrow = q0w + l15; if (qrow > 512) qrow = 512;
        const f16* qp = qbase + (size_t)qrow * RS + g * 8;
        qf[0] = *(const f16x8*)(qp);
        qf[1] = *(const f16x8*)(qp + 32);
    }

    f32x4v zero = {0.f, 0.f, 0.f, 0.f};
    f32x4v O[4]; float m[4], l[4];
    #pragma unroll
    for (int i = 0; i < 4; i++) { O[i] = zero; m[i] = -INFINITY; l[i] = 0.f; }

    int jt0 = 0;
    if (q0w > 0) { int fmin = (q0w - 1) >> 4; jt0 = (fmin * 16 + 1) >> 6; }

    int jrow[4];
    #pragma unroll
    for (int jf = 0; jf < 4; jf++) jrow[jf] = jf * 16 + l15;

    auto loadK = [&](int j0, f16x8* kr) {
        #pragma unroll
        for (int s = 0; s < 2; s++)
            #pragma unroll
            for (int jf = 0; jf < 4; jf++) {
                int j = j0 + jrow[jf]; if (j > 512) j = 512;
                kr[s * 4 + jf] = *(const f16x8*)(kbase + (size_t)j * RS + s * 32 + g * 8);
            }
    };

    int jt = jt0 + third;
    f16x8 kreg[8];
    if (jt < 9) loadK(jt * 64, kreg);

    for (; jt < 9; jt += SPLITS) {
        int j0 = jt * 64;
        f16x8 vreg[8];
        #pragma unroll
        for (int s = 0; s < 2; s++)
            #pragma unroll
            for (int df = 0; df < 4; df++)
                vreg[s * 4 + df] = *(const f16x8*)(vtb + (size_t)(df * 16 + l15) * 576 + j0 + s * 32 + g * 8);
        f32x4v S[4];
        #pragma unroll
        for (int jf = 0; jf < 4; jf++) S[jf] = zero;
        #pragma unroll
        for (int s = 0; s < 2; s++)
            #pragma unroll
            for (int jf = 0; jf < 4; jf++)
                S[jf] = __builtin_amdgcn_mfma_f32_16x16x32_f16(qf[s], kreg[s * 4 + jf], S[jf], 0, 0, 0);
        f16x8 knext[8];
        if (jt + SPLITS < 9) loadK((jt + SPLITS) * 64, knext);
        float pj[4][4];
        #pragma unroll
        for (int r = 0; r < 4; r++) {
            int qi = q0w + 4 * g + r;
            int fi = (qi == 0) ? -1 : ((qi - 1) >> 4);
            float mx = -INFINITY;
            #pragma unroll
            for (int jf = 0; jf < 4; jf++) {
                int j = j0 + jrow[jf];
                bool valid = (qi < 513) && (j < 513) &&
                             !((qi != 0) && ((j == 0) || (((j - 1) >> 4) < fi)));
                float sv = valid ? S[jf][r] * 0.125f : -INFINITY;
                pj[jf][r] = sv;
                mx = fmaxf(mx, sv);
            }
            mx = fmaxf(mx, __shfl_xor(mx, 1));
            mx = fmaxf(mx, __shfl_xor(mx, 2));
            mx = fmaxf(mx, __shfl_xor(mx, 4));
            mx = fmaxf(mx, __shfl_xor(mx, 8));
            float mn = fmaxf(m[r], mx);
            float alpha = (m[r] == -INFINITY) ? 0.f : __expf(m[r] - mn);
            float ls = 0.f;
            #pragma unroll
            for (int jf = 0; jf < 4; jf++) {
                float p = (pj[jf][r] == -INFINITY) ? 0.f : __expf(pj[jf][r] - mn);
                pj[jf][r] = p; ls += p;
            }
            ls += __shfl_xor(ls, 1); ls += __shfl_xor(ls, 2);
            ls += __shfl_xor(ls, 4); ls += __shfl_xor(ls, 8);
            l[r] = alpha * l[r] + ls;
            m[r] = mn;
            #pragma unroll
            for (int df = 0; df < 4; df++) O[df][r] *= alpha;
        }
        #pragma unroll
        for (int jf = 0; jf < 4; jf++)
            #pragma unroll
            for (int r = 0; r < 4; r++)
                Pl[w][4 * g + r][jf * 16 + l15] = (f16)pj[jf][r];
        #pragma unroll
        for (int s = 0; s < 2; s++) {
            f16x8 pf = *(const f16x8*)(&Pl[w][l15][s * 32 + g * 8]);
            #pragma unroll
            for (int df = 0; df < 4; df++)
                O[df] = __builtin_amdgcn_mfma_f32_16x16x32_f16(pf, vreg[s * 4 + df], O[df], 0, 0, 0);
        }
        #pragma unroll
        for (int i = 0; i < 8; i++) kreg[i] = knext[i];
    }

    int rowbase = third * 24624 + bh * 513;
    #pragma unroll
    for (int r = 0; r < 4; r++) {
        int qi = q0w + 4 * g + r;
        if (qi > 512) continue;
        size_t ro = (size_t)(rowbase + qi);
        #pragma unroll
        for (int df = 0; df < 4; df++)
            Op[ro * 64 + df * 16 + l15] = (f16)O[df][r];
        if (l15 == 0) {
            ml[ro * 2 + 0] = m[r];
            ml[ro * 2 + 1] = l[r];
        }
    }
}

// ---------------- head ----------------
__global__ __launch_bounds__(384) void head_kernel(
    const float* __restrict__ x, const float* __restrict__ lg, const float* __restrict__ lb,
    const float* __restrict__ w1, const float* __restrict__ b1,
    const float* __restrict__ w2, const float* __restrict__ b2,
    float* __restrict__ out)
{
    int b = blockIdx.x; int t = threadIdx.x;
    __shared__ float hs[384], h1[384];
    __shared__ float rs[6], rs2[6];
    const float* xp = x + (size_t)b * 513 * 384;
    float v = xp[t];
    float s = v, s2 = v * v;
    #pragma unroll
    for (int off = 32; off >= 1; off >>= 1) {
        s += __shfl_down(s, off); s2 += __shfl_down(s2, off);
    }
    if ((t & 63) == 0) { rs[t >> 6] = s; rs2[t >> 6] = s2; }
    __syncthreads();
    float S = 0.f, S2 = 0.f;
    #pragma unroll
    for (int i = 0; i < 6; i++) { S += rs[i]; S2 += rs2[i]; }
    float mu = S * (1.f / 384.f);
    float var = S2 * (1.f / 384.f) - mu * mu;
    float rstd = rsqrtf(var + EPSV);
    hs[t] = (v - mu) * rstd * lg[t] + lb[t];
    __syncthreads();
    const float* wr = w1 + (size_t)t * 384;
    float acc = b1[t];
    for (int c = 0; c < 384; c += 4) {
        float4 w4 = *reinterpret_cast<const float4*>(wr + c);
        acc += w4.x * hs[c] + w4.y * hs[c + 1] + w4.z * hs[c + 2] + w4.w * hs[c + 3];
    }
    h1[t] = gelu_f(acc);
    __syncthreads();
    float p0 = h1[t] * w2[t], p1 = h1[t] * w2[384 + t];
    #pragma unroll
    for (int off = 32; off >= 1; off >>= 1) {
        p0 += __shfl_down(p0, off); p1 += __shfl_down(p1, off);
    }
    if ((t & 63) == 0) { rs[t >> 6] = p0; rs2[t >> 6] = p1; }
    __syncthreads();
    if (t == 0) {
        float a0 = b2[0], a1 = b2[1];
        #pragma unroll
        for (int i = 0; i < 6; i++) { a0 += rs[i]; a1 += rs2[i]; }
        out[b * 2 + 0] = 1.f / (1.f + expf(-a0));
        out[b * 2 + 1] = 1.f / (1.f + expf(-a1));
    }
}

static inline int cdiv(int a, int b) { return (a + b - 1) / b; }

extern "C" void kernel_launch(void* const* d_in, const int* in_sizes, int n_in,
                              void* d_out, int out_size, void* d_ws, size_t ws_size,
                              hipStream_t stream)
{
    const float* frames  = (const float*)d_in[0];
    const float* conv1_w = (const float*)d_in[1];
    const float* bn1_g = (const float*)d_in[2]; const float* bn1_b = (const float*)d_in[3];
    const float* bn1_m = (const float*)d_in[4]; const float* bn1_v = (const float*)d_in[5];
    const float* conv2_w = (const float*)d_in[6];
    const float* bn2_g = (const float*)d_in[7]; const float* bn2_b = (const float*)d_in[8];
    const float* bn2_m = (const float*)d_in[9]; const float* bn2_v = (const float*)d_in[10];
    const float* conv3_w = (const float*)d_in[11];
    const float* bn3_g = (const float*)d_in[12]; const float* bn3_b = (const float*)d_in[13];
    const float* bn3_m = (const float*)d_in[14]; const float* bn3_v = (const float*)d_in[15];
    const float* proj_w = (const float*)d_in[16];
    const float* dw_w = (const float*)d_in[17]; const float* dw_b = (const float*)d_in[18];
    const float* pw_w = (const float*)d_in[19]; const float* pw_b = (const float*)d_in[20];
    const float* tnorm_g = (const float*)d_in[21]; const float* tnorm_b = (const float*)d_in[22];
    const float* frame_pos = (const float*)d_in[23];
    const float* patch_pos = (const float*)d_in[24];
    const float* cls_token = (const float*)d_in[25];
    const float* cls_pos = (const float*)d_in[26];
    const float* qkv_w = (const float*)d_in[27]; const float* qkv_b = (const float*)d_in[28];
    const float* out_w = (const float*)d_in[29]; const float* out_b = (const float*)d_in[30];
    const float* ln1_g = (const float*)d_in[31]; const float* ln1_b = (const float*)d_in[32];
    const float* ln2_g = (const float*)d_in[33]; const float* ln2_b = (const float*)d_in[34];
    const float* ffn_w1 = (const float*)d_in[35]; const float* ffn_b1 = (const float*)d_in[36];
    const float* ffn_w2 = (const float*)d_in[37]; const float* ffn_b2 = (const float*)d_in[38];
    const float* head_ln_g = (const float*)d_in[39]; const float* head_ln_b = (const float*)d_in[40];
    const float* head_w1 = (const float*)d_in[41]; const float* head_b1 = (const float*)d_in[42];
    const float* head_w2 = (const float*)d_in[43]; const float* head_b2 = (const float*)d_in[44];
    (void)in_sizes; (void)n_in; (void)out_size; (void)ws_size;

    char* base = (char*)d_ws;
    size_t off = 0;
    auto alloc = [&](size_t bytes) { void* p = base + off; off = (off + bytes + 255) & ~(size_t)255; return p; };

    // persistent region
    f16* wtotal = (f16*)alloc((size_t)10960896 * 2);
    f16* projw16 = wtotal;
    f16* pw16    = wtotal + 49152;
    f16* qkvw16  = wtotal + 344064;
    f16* outw16  = wtotal + 2998272;
    f16* f1w16   = wtotal + 3883008;
    f16* f2w16   = wtotal + 7421952;
    f16* c1wB    = (f16*)alloc(1024 * 2);
    f16* c2w16   = (f16*)alloc((size_t)64 * 288 * 2);
    f16* c3w16   = (f16*)alloc((size_t)128 * 576 * 2);
    f16* pooled  = (f16*)alloc((size_t)4096 * 128 * 2);
    float* tc    = (float*)alloc((size_t)4096 * 384 * 4);

    // union region: stem scratch vs mixer/transformer scratch
    size_t ustart = off;
    f16* c1h = (f16*)alloc((size_t)256 * 64 * 64 * 32 * 2);
    f16* c2h = (f16*)alloc((size_t)256 * 32 * 32 * 64 * 2);
    f16* c3h = (f16*)alloc((size_t)256 * 16 * 16 * 128 * 2);
    size_t uend_stem = off;
    off = ustart;
    float* mA = (float*)alloc((size_t)4096 * 384 * 4);
    float* mB = (float*)alloc((size_t)4096 * 384 * 4);
    f16*   mh = (f16*)alloc((size_t)4096 * 384 * 2);
    float* xb   = (float*)alloc((size_t)8 * 513 * 384 * 4);
    f16*   qkvb = (f16*)alloc((size_t)8 * 513 * 1152 * 2);
    f16*   vTb  = (f16*)alloc((size_t)48 * 64 * 576 * 2);
    f16*   ffb  = (f16*)alloc((size_t)8 * 513 * 1536 * 2);
    f16*   Opart = (f16*)alloc((size_t)SPLITS * 24624 * 64 * 2);
    float* mlpart = (float*)alloc((size_t)SPLITS * 24624 * 2 * 4);
    if (off < uend_stem) off = uend_stem;

    // ---------- weight conversion ----------
    cvt_all_kernel<<<4096, 256, 0, stream>>>(
        proj_w, pw_w, qkv_w, out_w, ffn_w1, ffn_w2, wtotal);
    conv1_w_prep_kernel<<<4, 256, 0, stream>>>(conv1_w, bn1_g, bn1_v, c1wB);
    conv_w_reorder_kernel<<<cdiv(64 * 288, 256), 256, 0, stream>>>(conv2_w, c2w16, 64, 32);
    conv_w_reorder_kernel<<<cdiv(128 * 576, 256), 256, 0, stream>>>(conv3_w, c3w16, 128, 64);

    // ---------- conv stem, full 256-frame batch ----------
    conv1_mfma_kernel<<<256 * 16, 256, 0, stream>>>(
        frames, c1wB, bn1_b, bn1_m, bn1_g, bn1_v, c1h);
    convg_kernel<32, 64, 64><<<dim3(4096, 1), 256, 0, stream>>>(
        c1h, c2w16, bn2_g, bn2_b, bn2_m, bn2_v, c2h);
    convg_kernel<64, 32, 128><<<dim3(1024, 2), 256, 0, stream>>>(
        c2h, c3w16, bn3_g, bn3_b, bn3_m, bn3_v, c3h);
    poolh_kernel<<<256, 256, 0, stream>>>(c3h, pooled, 256);
    // proj with TCMAP epilogue: writes directly into tc layout (b*16+p, t, d)
    gemm_k64_kernel<0, 0, 1><<<384, 256, 0, stream>>>(
        pooled, projw16, nullptr, nullptr, tc, 4096, 384, 128, 64);

    // ---------- temporal mixer ----------
    dwconv_kernel<<<cdiv(128 * 32 * 384, 256), 256, 0, stream>>>(
        tc, dw_w, dw_b, mh, 1);
    gemm_k64_kernel<0, 0, 0><<<384, 256, 0, stream>>>(
        mh, pw16, pw_b, tc, mA, 4096, 384, 384, 64);
    dwconv_kernel<<<cdiv(128 * 32 * 384, 256), 256, 0, stream>>>(
        mA, dw_w + 384 * 3, dw_b + 384, mh, 2);
    gemm_k64_kernel<0, 0, 0><<<384, 256, 0, stream>>>(
        mh, pw16 + 384 * 384, pw_b + 384, mA, mB, 4096, 384, 384, 64);

    // ---------- build transformer input x ----------
    build_x_kernel<<<128 * 32, 128, 0, stream>>>(
        mB, tc, tnorm_g, tnorm_b, frame_pos, patch_pos, xb);
    cls_kernel<<<cdiv(8 * 384, 256), 256, 0, stream>>>(cls_token, cls_pos, xb);

    // ---------- transformer ----------
    const int M = 8 * 513;        // 4104
    const int NR = cdiv(M, 64);   // 65
    for (int l = 0; l < 6; l++) {
        gemm_ln_kernel<0, 1><<<NR * 18, 256, 0, stream>>>(
            xb, ln1_g + (size_t)l * 384, ln1_b + (size_t)l * 384,
            qkvw16 + (size_t)l * 1152 * 384, qkv_b + (size_t)l * 1152,
            qkvb, vTb, M, 1152, NR);
        fattn_split_kernel<<<dim3(9, 48, SPLITS), 256, 0, stream>>>(qkvb, vTb, Opart, mlpart);
        gemm_comb_kernel<<<NR * 6, 256, 0, stream>>>(
            Opart, mlpart, outw16 + (size_t)l * 384 * 384, out_b + (size_t)l * 384,
            xb, M, NR);
        gemm_ln_kernel<1, 0><<<NR * 24, 256, 0, stream>>>(
            xb, ln2_g + (size_t)l * 384, ln2_b + (size_t)l * 384,
            f1w16 + (size_t)l * 1536 * 384, ffn_b1 + (size_t)l * 1536,
            ffb, nullptr, M, 1536, NR);
        gemm_k64_kernel<0, 0, 0><<<NR * 6, 256, 0, stream>>>(
            ffb, f2w16 + (size_t)l * 384 * 1536, ffn_b2 + (size_t)l * 384,
            xb, xb, M, 384, 1536, NR);
    }

    // ---------- head ----------
    head_kernel<<<8, 384, 0, stream>>>(
        xb, head_ln_g, head_ln_b, head_w1, head_b1, head_w2, head_b2, (float*)d_out);
}

// Round 12
// 842.762 us; speedup vs baseline: 1.4475x; 1.4475x over previous
//
#include <hip/hip_runtime.h>
#include <hip/hip_fp16.h>
#include <cstddef>

#define EPSV 1e-5f
#define SPLITS 4

typedef _Float16 f16;
typedef _Float16 f16x8 __attribute__((ext_vector_type(8)));
typedef float f32x4v __attribute__((ext_vector_type(4)));

__device__ __forceinline__ float gelu_f(float x) {
    return 0.5f * x * (1.0f + erff(x * 0.7071067811865476f));
}

// branch-free tanh-GELU: x*(1 - 1/(exp2(z)+1)), z = x*(2.3025851+0.10296103 x^2)
__device__ __forceinline__ float gelu_fast(float x) {
    float x2 = x * x;
    float z = x * fmaf(0.10296103f, x2, 2.3025851f);
    float e = exp2f(z);
    float r = __builtin_amdgcn_rcpf(e + 1.0f);
    return fmaf(-x, r, x);
}

// ---------------- all-weights f32 -> f16 convert (one dispatch) ----------------
__global__ __launch_bounds__(256) void cvt_all_kernel(
    const float* __restrict__ p0, const float* __restrict__ p1,
    const float* __restrict__ p2, const float* __restrict__ p3,
    const float* __restrict__ p4, const float* __restrict__ p5,
    f16* __restrict__ dst)
{
    const int n = 10960896;
    for (int i = blockIdx.x * 256 + threadIdx.x; i < n; i += gridDim.x * 256) {
        const float* s; int off;
        if      (i <   49152) { s = p0; off = i; }
        else if (i <  344064) { s = p1; off = i -   49152; }
        else if (i < 2998272) { s = p2; off = i -  344064; }
        else if (i < 3883008) { s = p3; off = i - 2998272; }
        else if (i < 7421952) { s = p4; off = i - 3883008; }
        else                  { s = p5; off = i - 7421952; }
        dst[i] = (f16)s[off];
    }
}

// ---------------- conv weight reorder ----------------
__global__ __launch_bounds__(256) void conv_w_reorder_kernel(
    const float* __restrict__ w, f16* __restrict__ out, int CO, int CI)
{
    int n = CO * CI * 9;
    for (int i = blockIdx.x * 256 + threadIdx.x; i < n; i += gridDim.x * 256) {
        int t = i % 9; int r = i / 9;
        int ci = r % CI; int co = r / CI;
        out[(size_t)co * CI * 9 + t * CI + ci] = (f16)w[i];
    }
}

// ---------------- conv1 weight prep ----------------
__global__ __launch_bounds__(256) void conv1_w_prep_kernel(
    const float* __restrict__ w, const float* __restrict__ g,
    const float* __restrict__ vr, f16* __restrict__ wB)
{
    int i = blockIdx.x * 256 + threadIdx.x;
    if (i >= 1024) return;
    int co = i >> 5, k = i & 31;
    float inv = g[co] * rsqrtf(vr[co] + EPSV);
    wB[i] = (f16)((k < 25) ? w[co * 25 + k] * inv : 0.f);
}

// ---------------- conv1: 5x5 s2 p2 via MFMA implicit GEMM, NHWC f16, staged writes ----------------
__global__ __launch_bounds__(256) void conv1_mfma_kernel(
    const float* __restrict__ in, const f16* __restrict__ wB,
    const float* __restrict__ bt, const float* __restrict__ mn,
    const float* __restrict__ g, const float* __restrict__ vr,
    f16* __restrict__ out)
{
    __shared__ __align__(16) f16 inpH[35 * 36 + 8];
    __shared__ __align__(16) f16 Bs[32 * 32];
    __shared__ __align__(16) f16 stg[16 * 16 * 32];
    int bid = blockIdx.x;
    int n = bid >> 4; int tile = bid & 15;
    int ty0 = (tile >> 2) * 16, tx0 = (tile & 3) * 16;
    int t = threadIdx.x;
    const float* ip = in + (size_t)n * 16384;
    for (int e = t; e < 35 * 36; e += 256) {
        int r = e / 36, c = e - r * 36;
        int iy = ty0 * 2 - 2 + r, ix = tx0 * 2 - 2 + c;
        float v = ((unsigned)iy < 128u && (unsigned)ix < 128u && c < 35) ? ip[iy * 128 + ix] : 0.f;
        inpH[e] = (f16)v;
    }
    if (t < 128) {
        int row = t >> 2, seg = (t & 3) * 8;
        *(uint4*)(&Bs[row * 32 + seg]) = *(const uint4*)(wB + row * 32 + seg);
    }
    __syncthreads();
    int w = t >> 6, lane = t & 63;
    int l15 = lane & 15, gq = lane >> 4;
    f16x8 afr[4];
    #pragma unroll
    for (int i = 0; i < 4; i++) {
        int mt = 4 * w + i;
        f16 tmp[8];
        #pragma unroll
        for (int e = 0; e < 8; e++) {
            int kk = 8 * gq + e; if (kk > 24) kk = 24;
            int ky = kk / 5, kx = kk - ky * 5;
            tmp[e] = inpH[(2 * mt + ky) * 36 + 2 * l15 + kx];
        }
        afr[i] = *(f16x8*)tmp;
    }
    f16x8 bfr[2];
    bfr[0] = *(const f16x8*)(&Bs[l15 * 32 + 8 * gq]);
    bfr[1] = *(const f16x8*)(&Bs[(16 + l15) * 32 + 8 * gq]);
    f32x4v zero = {0.f, 0.f, 0.f, 0.f};
    f32x4v acc[4][2];
    #pragma unroll
    for (int i = 0; i < 4; i++) { acc[i][0] = zero; acc[i][1] = zero; }
    #pragma unroll
    for (int i = 0; i < 4; i++) {
        acc[i][0] = __builtin_amdgcn_mfma_f32_16x16x32_f16(afr[i], bfr[0], acc[i][0], 0, 0, 0);
        acc[i][1] = __builtin_amdgcn_mfma_f32_16x16x32_f16(afr[i], bfr[1], acc[i][1], 0, 0, 0);
    }
    float beta[2];
    #pragma unroll
    for (int nt = 0; nt < 2; nt++) {
        int co = nt * 16 + l15;
        float inv = g[co] * rsqrtf(vr[co] + EPSV);
        beta[nt] = bt[co] - mn[co] * inv;
    }
    // stage into LDS [y16][x16][ch32], then coalesced 64B/pixel writes
    #pragma unroll
    for (int i = 0; i < 4; i++) {
        int y = 4 * w + i;
        #pragma unroll
        for (int q = 0; q < 4; q++) {
            int x = 4 * gq + q;
            #pragma unroll
            for (int nt = 0; nt < 2; nt++)
                stg[(y * 16 + x) * 32 + nt * 16 + l15] =
                    (f16)gelu_fast(acc[i][nt][q] + beta[nt]);
        }
    }
    __syncthreads();
    {
        int y = t >> 4, x = t & 15;
        size_t ob = (((size_t)n * 64 + ty0 + y) * 64 + tx0 + x) * 32;
        const uint4* sp = (const uint4*)(stg + t * 32);
        uint4* dp = (uint4*)(out + ob);
        dp[0] = sp[0]; dp[1] = sp[1]; dp[2] = sp[2]; dp[3] = sp[3];
    }
}

// ---------------- implicit-GEMM conv 3x3 s2 p1, NHWC f16, MFMA, staged writes ----------------
template<int CI, int HI, int CO>
__global__ __launch_bounds__(256) void convg_kernel(
    const f16* __restrict__ in, const f16* __restrict__ wr_,
    const float* __restrict__ g, const float* __restrict__ bt,
    const float* __restrict__ mn, const float* __restrict__ vr,
    f16* __restrict__ out)
{
    constexpr int HO = HI / 2;
    constexpr int HOB = (HO == 32) ? 5 : 4;
    constexpr int K = 9 * CI;
    __shared__ __align__(16) f16 ABs[2 * 64 * 40];   // loads; reused as 64x64 C stage
    f16* As = ABs;
    f16* Bs = ABs + 64 * 40;
    int tid = threadIdx.x;
    int bm = blockIdx.x * 64;
    int bn = blockIdx.y * 64;
    int lrow = tid >> 2, lseg = tid & 3;
    int w = tid >> 6, lane = tid & 63;
    int wr = (w >> 1) * 32, wc = (w & 1) * 32;
    int l15 = lane & 15, l4 = lane >> 4;
    int gp = bm + lrow;
    int pn = gp >> (2 * HOB);
    int prem = gp & ((1 << (2 * HOB)) - 1);
    int oy = prem >> HOB, ox = prem & (HO - 1);

    f32x4v zero = {0.f, 0.f, 0.f, 0.f};
    f32x4v acc[2][2];
    acc[0][0] = zero; acc[0][1] = zero; acc[1][0] = zero; acc[1][1] = zero;

    auto loadTile = [&](int k0, uint4& av, uint4& bv) {
        int tap = k0 / CI;
        int cio = k0 - tap * CI;
        int ky = tap / 3, kx = tap - ky * 3;
        int iy = oy * 2 - 1 + ky, ix = ox * 2 - 1 + kx;
        av = make_uint4(0u, 0u, 0u, 0u);
        if ((unsigned)iy < (unsigned)HI && (unsigned)ix < (unsigned)HI)
            av = *(const uint4*)(in + (((size_t)(pn * HI + iy)) * HI + ix) * CI + cio + lseg * 8);
        bv = *(const uint4*)(wr_ + (size_t)(bn + lrow) * K + k0 + lseg * 8);
    };

    uint4 ra, rb;
    loadTile(0, ra, rb);
    for (int k0 = 0; k0 < K; k0 += 32) {
        __syncthreads();
        *(uint4*)(&As[lrow * 40 + lseg * 8]) = ra;
        *(uint4*)(&Bs[lrow * 40 + lseg * 8]) = rb;
        if (k0 + 32 < K) loadTile(k0 + 32, ra, rb);
        __syncthreads();
        f16x8 a0 = *(const f16x8*)(&As[(wr + l15) * 40 + l4 * 8]);
        f16x8 a1 = *(const f16x8*)(&As[(wr + 16 + l15) * 40 + l4 * 8]);
        f16x8 b0 = *(const f16x8*)(&Bs[(wc + l15) * 40 + l4 * 8]);
        f16x8 b1 = *(const f16x8*)(&Bs[(wc + 16 + l15) * 40 + l4 * 8]);
        acc[0][0] = __builtin_amdgcn_mfma_f32_16x16x32_f16(a0, b0, acc[0][0], 0, 0, 0);
        acc[0][1] = __builtin_amdgcn_mfma_f32_16x16x32_f16(a0, b1, acc[0][1], 0, 0, 0);
        acc[1][0] = __builtin_amdgcn_mfma_f32_16x16x32_f16(a1, b0, acc[1][0], 0, 0, 0);
        acc[1][1] = __builtin_amdgcn_mfma_f32_16x16x32_f16(a1, b1, acc[1][1], 0, 0, 0);
    }
    float inv[2], beta[2];
    #pragma unroll
    for (int ni = 0; ni < 2; ni++) {
        int col = bn + wc + ni * 16 + l15;
        float iv = g[col] * rsqrtf(vr[col] + EPSV);
        inv[ni] = iv; beta[ni] = bt[col] - mn[col] * iv;
    }
    // stage C tile [px64][ch64] into LDS, then coalesced writes
    __syncthreads();
    #pragma unroll
    for (int mi = 0; mi < 2; mi++) {
        #pragma unroll
        for (int q = 0; q < 4; q++) {
            int px = wr + mi * 16 + l4 * 4 + q;
            #pragma unroll
            for (int ni = 0; ni < 2; ni++) {
                int ch = wc + ni * 16 + l15;
                float v = acc[mi][ni][q] * inv[ni] + beta[ni];
                ABs[px * 64 + ch] = (f16)gelu_fast(v);
            }
        }
    }
    __syncthreads();
    {
        int px = tid >> 2, seg = (tid & 3) * 16;
        size_t ob = (size_t)(bm + px) * CO + bn + seg;
        *(uint4*)(out + ob)     = *(const uint4*)(&ABs[px * 64 + seg]);
        *(uint4*)(out + ob + 8) = *(const uint4*)(&ABs[px * 64 + seg + 8]);
    }
}

// ---------------- 4x4 avg pool NHWC f16 ----------------
__global__ __launch_bounds__(256) void poolh_kernel(
    const f16* __restrict__ in, f16* __restrict__ out, int NC)
{
    int idx = blockIdx.x * 256 + threadIdx.x;
    if (idx >= NC * 16 * 16) return;
    int cc = idx & 15; int npl = idx >> 4;
    int c0 = cc * 8;
    int n = npl >> 4; int p = npl & 15;
    int ph = p >> 2, pw = p & 3;
    const f16* base = in + (((size_t)(n * 16 + ph * 4)) * 16 + pw * 4) * 128 + c0;
    float s[8] = {};
    #pragma unroll
    for (int dy = 0; dy < 4; dy++)
        #pragma unroll
        for (int dx = 0; dx < 4; dx++) {
            f16x8 v = *(const f16x8*)(base + (dy * 16 + dx) * 128);
            #pragma unroll
            for (int u = 0; u < 8; u++) s[u] += (float)v[u];
        }
    f16* op = out + (size_t)npl * 128 + c0;
    #pragma unroll
    for (int u = 0; u < 8; u++) op[u] = (f16)(s[u] * 0.0625f);
}

// ---------------- MFMA f16 NT GEMM, 64x64 tile, BK=64, XCD-swizzled 1D grid ----------------
template<int OUTF16, int ACT, int VTRANS, int TCMAP>
__global__ __launch_bounds__(256) void gemm_k64_kernel(
    const f16* __restrict__ A, const f16* __restrict__ B,
    const float* __restrict__ bias, const float* __restrict__ res,
    void* __restrict__ Cv, f16* __restrict__ vT, int M, int N, int K, int nrow)
{
    __shared__ __align__(16) f16 As[64 * 72];
    __shared__ __align__(16) f16 Bs[64 * 72];
    int nb = gridDim.x;
    int q = nb >> 3, r = nb & 7;
    int xcd = blockIdx.x & 7, pos = blockIdx.x >> 3;
    int logical = (xcd < r ? xcd * (q + 1) : r * (q + 1) + (xcd - r) * q) + pos;
    int brow = logical % nrow, bcol = logical / nrow;
    int bm = brow * 64, bn = bcol * 64;

    int tid = threadIdx.x;
    int lrow = tid >> 2, lseg = (tid & 3) * 16;
    int w = tid >> 6, lane = tid & 63;
    int wr = (w >> 1) * 32, wc = (w & 1) * 32;
    int l15 = lane & 15, l4 = lane >> 4;
    f32x4v zero = {0.f, 0.f, 0.f, 0.f};
    f32x4v acc[2][2];
    acc[0][0] = zero; acc[0][1] = zero; acc[1][0] = zero; acc[1][1] = zero;

    int arow = bm + lrow;
    bool aok = (arow < M);
    const f16* ap = A + (size_t)arow * K + lseg;
    const f16* bp = B + (size_t)(bn + lrow) * K + lseg;

    uint4 ra0 = make_uint4(0u,0u,0u,0u), ra1 = ra0, rb0, rb1;
    if (aok) { ra0 = *(const uint4*)(ap); ra1 = *(const uint4*)(ap + 8); }
    rb0 = *(const uint4*)(bp); rb1 = *(const uint4*)(bp + 8);

    int nt = K >> 6;
    for (int t = 0; t < nt; t++) {
        __syncthreads();
        *(uint4*)(&As[lrow * 72 + lseg])     = ra0;
        *(uint4*)(&As[lrow * 72 + lseg + 8]) = ra1;
        *(uint4*)(&Bs[lrow * 72 + lseg])     = rb0;
        *(uint4*)(&Bs[lrow * 72 + lseg + 8]) = rb1;
        if (t + 1 < nt) {
            int k0 = (t + 1) << 6;
            if (aok) { ra0 = *(const uint4*)(ap + k0); ra1 = *(const uint4*)(ap + k0 + 8); }
            rb0 = *(const uint4*)(bp + k0); rb1 = *(const uint4*)(bp + k0 + 8);
        }
        __syncthreads();
        #pragma unroll
        for (int s = 0; s < 2; s++) {
            f16x8 a0 = *(const f16x8*)(&As[(wr + l15) * 72 + s * 32 + l4 * 8]);
            f16x8 a1 = *(const f16x8*)(&As[(wr + 16 + l15) * 72 + s * 32 + l4 * 8]);
            f16x8 b0 = *(const f16x8*)(&Bs[(wc + l15) * 72 + s * 32 + l4 * 8]);
            f16x8 b1 = *(const f16x8*)(&Bs[(wc + 16 + l15) * 72 + s * 32 + l4 * 8]);
            acc[0][0] = __builtin_amdgcn_mfma_f32_16x16x32_f16(a0, b0, acc[0][0], 0, 0, 0);
            acc[0][1] = __builtin_amdgcn_mfma_f32_16x16x32_f16(a0, b1, acc[0][1], 0, 0, 0);
            acc[1][0] = __builtin_amdgcn_mfma_f32_16x16x32_f16(a1, b0, acc[1][0], 0, 0, 0);
            acc[1][1] = __builtin_amdgcn_mfma_f32_16x16x32_f16(a1, b1, acc[1][1], 0, 0, 0);
        }
    }

    if (VTRANS && bn >= 768) {
        __syncthreads();
        f16* tile = As;   // [64][66]
        #pragma unroll
        for (int mi = 0; mi < 2; mi++)
            #pragma unroll
            for (int qq = 0; qq < 4; qq++) {
                int rl = wr + mi * 16 + l4 * 4 + qq;
                #pragma unroll
                for (int ni = 0; ni < 2; ni++) {
                    int dl = wc + ni * 16 + l15;
                    float v = acc[mi][ni][qq] + bias[bn + dl];
                    tile[dl * 66 + rl] = (f16)v;
                }
            }
        __syncthreads();
        int h = (bn - 768) >> 6;
        int j = tid & 63, dbase = tid >> 6;
        int trow = bm + j;
        if (trow < M) {
            int b = trow / 513;
            int jj = trow - b * 513;
            f16* vb = vT + ((size_t)(b * 6 + h) * 64) * 576 + jj;
            #pragma unroll
            for (int it = 0; it < 16; it++) {
                int d = dbase * 16 + it;
                vb[(size_t)d * 576] = tile[d * 66 + j];
            }
        }
        return;
    }
    #pragma unroll
    for (int mi = 0; mi < 2; mi++) {
        #pragma unroll
        for (int qq = 0; qq < 4; qq++) {
            int row = bm + wr + mi * 16 + l4 * 4 + qq;
            if (row >= M) continue;
            #pragma unroll
            for (int ni = 0; ni < 2; ni++) {
                int col = bn + wc + ni * 16 + l15;
                float v = acc[mi][ni][qq];
                if (bias) v += bias[col];
                if (ACT == 1) v = gelu_fast(v);
                if (res) v += res[(size_t)row * N + col];
                int orow = row;
                if (TCMAP) orow = (row & ~511) | ((row & 15) << 5) | ((row >> 4) & 31);
                if (OUTF16) ((f16*)Cv)[(size_t)orow * N + col] = (f16)v;
                else ((float*)Cv)[(size_t)orow * N + col] = v;
            }
        }
    }
}

// ---------------- MFMA f16 NT GEMM, 64x128 tile (wave 32x64), BK=64 ----------------
template<int ACT>
__global__ __launch_bounds__(256) void gemm_kn128_kernel(
    const f16* __restrict__ A, const f16* __restrict__ B,
    const float* __restrict__ bias, f16* __restrict__ C,
    int M, int N, int K, int nrow)
{
    __shared__ __align__(16) f16 As[64 * 72];
    __shared__ __align__(16) f16 Bs[128 * 72];
    int nb = gridDim.x;
    int q = nb >> 3, r = nb & 7;
    int xcd = blockIdx.x & 7, pos = blockIdx.x >> 3;
    int logical = (xcd < r ? xcd * (q + 1) : r * (q + 1) + (xcd - r) * q) + pos;
    int brow = logical % nrow, bcol = logical / nrow;
    int bm = brow * 64, bn = bcol * 128;

    int tid = threadIdx.x;
    int w = tid >> 6, lane = tid & 63;
    int wr = (w >> 1) * 32, wc = (w & 1) * 64;
    int l15 = lane & 15, l4 = lane >> 4;
    int alrow = tid >> 2, alseg = (tid & 3) * 16;
    int blrow = tid >> 1, blseg = (tid & 1) * 32;

    f32x4v zero = {0.f, 0.f, 0.f, 0.f};
    f32x4v acc[2][4];
    #pragma unroll
    for (int i = 0; i < 2; i++)
        #pragma unroll
        for (int j = 0; j < 4; j++) acc[i][j] = zero;

    int arow = bm + alrow;
    bool aok = (arow < M);
    const f16* ap = A + (size_t)arow * K + alseg;
    const f16* bp = B + (size_t)(bn + blrow) * K + blseg;

    uint4 ra0 = make_uint4(0u,0u,0u,0u), ra1 = ra0;
    uint4 rb0, rb1, rb2, rb3;
    if (aok) { ra0 = *(const uint4*)(ap); ra1 = *(const uint4*)(ap + 8); }
    rb0 = *(const uint4*)(bp);      rb1 = *(const uint4*)(bp + 8);
    rb2 = *(const uint4*)(bp + 16); rb3 = *(const uint4*)(bp + 24);

    int ntiles = K >> 6;
    for (int t = 0; t < ntiles; t++) {
        __syncthreads();
        *(uint4*)(&As[alrow * 72 + alseg])     = ra0;
        *(uint4*)(&As[alrow * 72 + alseg + 8]) = ra1;
        *(uint4*)(&Bs[blrow * 72 + blseg])      = rb0;
        *(uint4*)(&Bs[blrow * 72 + blseg + 8])  = rb1;
        *(uint4*)(&Bs[blrow * 72 + blseg + 16]) = rb2;
        *(uint4*)(&Bs[blrow * 72 + blseg + 24]) = rb3;
        if (t + 1 < ntiles) {
            int k0 = (t + 1) << 6;
            if (aok) { ra0 = *(const uint4*)(ap + k0); ra1 = *(const uint4*)(ap + k0 + 8); }
            rb0 = *(const uint4*)(bp + k0);      rb1 = *(const uint4*)(bp + k0 + 8);
            rb2 = *(const uint4*)(bp + k0 + 16); rb3 = *(const uint4*)(bp + k0 + 24);
        }
        __syncthreads();
        #pragma unroll
        for (int s = 0; s < 2; s++) {
            f16x8 a0 = *(const f16x8*)(&As[(wr + l15) * 72 + s * 32 + l4 * 8]);
            f16x8 a1 = *(const f16x8*)(&As[(wr + 16 + l15) * 72 + s * 32 + l4 * 8]);
            #pragma unroll
            for (int j = 0; j < 4; j++) {
                f16x8 bf = *(const f16x8*)(&Bs[(wc + j * 16 + l15) * 72 + s * 32 + l4 * 8]);
                acc[0][j] = __builtin_amdgcn_mfma_f32_16x16x32_f16(a0, bf, acc[0][j], 0, 0, 0);
                acc[1][j] = __builtin_amdgcn_mfma_f32_16x16x32_f16(a1, bf, acc[1][j], 0, 0, 0);
            }
        }
    }
    #pragma unroll
    for (int mi = 0; mi < 2; mi++) {
        #pragma unroll
        for (int qq = 0; qq < 4; qq++) {
            int row = bm + wr + mi * 16 + l4 * 4 + qq;
            if (row >= M) continue;
            #pragma unroll
            for (int j = 0; j < 4; j++) {
                int col = bn + wc + j * 16 + l15;
                float v = acc[mi][j][qq];
                if (bias) v += bias[col];
                if (ACT == 1) v = gelu_fast(v);
                C[(size_t)row * N + col] = (f16)v;
            }
        }
    }
}

// ---------------- depthwise temporal conv + bias + gelu -> f16 ----------------
__global__ __launch_bounds__(256) void dwconv_kernel(
    const float* __restrict__ in, const float* __restrict__ w,
    const float* __restrict__ bias, f16* __restrict__ out, int dil)
{
    int idx = blockIdx.x * 256 + threadIdx.x;
    if (idx >= 128 * 32 * 384) return;
    int d = idx % 384; int t = (idx / 384) & 31; int s = idx / (384 * 32);
    const float* ip = in + (size_t)s * 32 * 384 + d;
    float acc = bias[d];
    #pragma unroll
    for (int k = 0; k < 3; k++) {
        int tt = t + (k - 1) * dil;
        if ((unsigned)tt < 32u) acc += w[d * 3 + k] * ip[tt * 384];
    }
    out[idx] = (f16)gelu_fast(acc);
}

// ---------------- LayerNorm: wave-per-row, shfl reduce, f32 in -> f16 out ----------------
__global__ __launch_bounds__(256) void ln_wave_kernel(
    const float* __restrict__ in,
    const float* __restrict__ g, const float* __restrict__ b,
    f16* __restrict__ out, int rows)
{
    int w = threadIdx.x >> 6, lane = threadIdx.x & 63;
    int row = blockIdx.x * 4 + w;
    if (row >= rows) return;
    const float* ip = in + (size_t)row * 384;
    float x[6]; float s = 0.f, s2 = 0.f;
    #pragma unroll
    for (int k = 0; k < 6; k++) {
        float v = ip[lane + 64 * k];
        x[k] = v; s += v; s2 += v * v;
    }
    #pragma unroll
    for (int off = 1; off < 64; off <<= 1) {
        s += __shfl_xor(s, off); s2 += __shfl_xor(s2, off);
    }
    float mu = s * (1.f / 384.f);
    float var = s2 * (1.f / 384.f) - mu * mu;
    float rs = rsqrtf(var + EPSV);
    #pragma unroll
    for (int k = 0; k < 6; k++) {
        int c = lane + 64 * k;
        out[(size_t)row * 384 + c] = (f16)((x[k] - mu) * rs * g[c] + b[c]);
    }
}

// ---------------- mixer-final LN + positional add ----------------
__global__ __launch_bounds__(128) void build_x_kernel(
    const float* __restrict__ mix, const float* __restrict__ tc,
    const float* __restrict__ tg, const float* __restrict__ tb,
    const float* __restrict__ fpos, const float* __restrict__ ppos,
    float* __restrict__ x)
{
    int row = blockIdx.x;
    int t = row & 31; int bp = row >> 5;
    int p = bp & 15; int b = bp >> 4;
    int tid = threadIdx.x;
    const float* ip = mix + (size_t)row * 384;
    const float* ip2 = tc + (size_t)row * 384;
    __shared__ float red[128], red2[128];
    float v[3]; float s = 0.f, s2 = 0.f;
    #pragma unroll
    for (int j = 0; j < 3; j++) {
        float val = ip[tid + 128 * j] + ip2[tid + 128 * j];
        v[j] = val; s += val; s2 += val * val;
    }
    red[tid] = s; red2[tid] = s2; __syncthreads();
    for (int off = 64; off >= 1; off >>= 1) {
        if (tid < off) { red[tid] += red[tid + off]; red2[tid] += red2[tid + off]; }
        __syncthreads();
    }
    float mu = red[0] * (1.f / 384.f);
    float var = red2[0] * (1.f / 384.f) - mu * mu;
    float rs = rsqrtf(var + EPSV);
    size_t xbase = ((size_t)b * 513 + 1 + t * 16 + p) * 384;
    #pragma unroll
    for (int j = 0; j < 3; j++) {
        int c = tid + 128 * j;
        float y = (v[j] - mu) * rs * tg[c] + tb[c] + fpos[t * 384 + c] + ppos[p * 384 + c];
        x[xbase + c] = y;
    }
}

__global__ __launch_bounds__(256) void cls_kernel(
    const float* __restrict__ ct, const float* __restrict__ cp, float* __restrict__ x)
{
    int idx = blockIdx.x * 256 + threadIdx.x;
    if (idx >= 8 * 384) return;
    int c = idx % 384; int b = idx / 384;
    x[(size_t)b * 513 * 384 + c] = ct[c] + cp[c];
}

// ---------------- flash attention, SPLITS-way j-split + K/V register prefetch ----------------
__global__ __launch_bounds__(256) void fattn_split_kernel(
    const f16* __restrict__ qkv, const f16* __restrict__ vT,
    f16* __restrict__ Op, float* __restrict__ ml)
{
    __shared__ __align__(16) f16 Pl[4][16][72];
    int qt = blockIdx.x;
    int bh = blockIdx.y; int h = bh % 6; int b = bh / 6;
    int third = blockIdx.z;
    int tid = threadIdx.x;
    int w = tid >> 6, lane = tid & 63;
    int l15 = lane & 15, g = lane >> 4;
    int q0w = qt * 64 + w * 16;
    if (q0w > 512) return;
    const size_t RS = 1152;
    const f16* qbase = qkv + (size_t)b * 513 * RS + h * 64;
    const f16* kbase = qbase + 384;
    const f16* vtb = vT + (size_t)bh * 64 * 576;

    f16x8 qf[2];
    {
        int qrow = q0w + l15; if (qrow > 512) qrow = 512;
        const f16* qp = qbase + (size_t)qrow * RS + g * 8;
        qf[0] = *(const f16x8*)(qp);
        qf[1] = *(const f16x8*)(qp + 32);
    }

    f32x4v zero = {0.f, 0.f, 0.f, 0.f};
    f32x4v O[4]; float m[4], l[4];
    #pragma unroll
    for (int i = 0; i < 4; i++) { O[i] = zero; m[i] = -INFINITY; l[i] = 0.f; }

    int jt0 = 0;
    if (q0w > 0) { int fmin = (q0w - 1) >> 4; jt0 = (fmin * 16 + 1) >> 6; }

    int jrow[4];
    #pragma unroll
    for (int jf = 0; jf < 4; jf++) jrow[jf] = jf * 16 + l15;

    auto loadK = [&](int j0, f16x8* kr) {
        #pragma unroll
        for (int s = 0; s < 2; s++)
            #pragma unroll
            for (int jf = 0; jf < 4; jf++) {
                int j = j0 + jrow[jf]; if (j > 512) j = 512;
                kr[s * 4 + jf] = *(const f16x8*)(kbase + (size_t)j * RS + s * 32 + g * 8);
            }
    };

    int jt = jt0 + third;
    f16x8 kreg[8];
    if (jt < 9) loadK(jt * 64, kreg);

    for (; jt < 9; jt += SPLITS) {
        int j0 = jt * 64;
        f16x8 vreg[8];
        #pragma unroll
        for (int s = 0; s < 2; s++)
            #pragma unroll
            for (int df = 0; df < 4; df++)
                vreg[s * 4 + df] = *(const f16x8*)(vtb + (size_t)(df * 16 + l15) * 576 + j0 + s * 32 + g * 8);
        f32x4v S[4];
        #pragma unroll
        for (int jf = 0; jf < 4; jf++) S[jf] = zero;
        #pragma unroll
        for (int s = 0; s < 2; s++)
            #pragma unroll
            for (int jf = 0; jf < 4; jf++)
                S[jf] = __builtin_amdgcn_mfma_f32_16x16x32_f16(qf[s], kreg[s * 4 + jf], S[jf], 0, 0, 0);
        f16x8 knext[8];
        if (jt + SPLITS < 9) loadK((jt + SPLITS) * 64, knext);
        float pj[4][4];
        #pragma unroll
        for (int r = 0; r < 4; r++) {
            int qi = q0w + 4 * g + r;
            int fi = (qi == 0) ? -1 : ((qi - 1) >> 4);
            float mx = -INFINITY;
            #pragma unroll
            for (int jf = 0; jf < 4; jf++) {
                int j = j0 + jrow[jf];
                bool valid = (qi < 513) && (j < 513) &&
                             !((qi != 0) && ((j == 0) || (((j - 1) >> 4) < fi)));
                float sv = valid ? S[jf][r] * 0.125f : -INFINITY;
                pj[jf][r] = sv;
                mx = fmaxf(mx, sv);
            }
            mx = fmaxf(mx, __shfl_xor(mx, 1));
            mx = fmaxf(mx, __shfl_xor(mx, 2));
            mx = fmaxf(mx, __shfl_xor(mx, 4));
            mx = fmaxf(mx, __shfl_xor(mx, 8));
            float mn = fmaxf(m[r], mx);
            float alpha = (m[r] == -INFINITY) ? 0.f : __expf(m[r] - mn);
            float ls = 0.f;
            #pragma unroll
            for (int jf = 0; jf < 4; jf++) {
                float p = (pj[jf][r] == -INFINITY) ? 0.f : __expf(pj[jf][r] - mn);
                pj[jf][r] = p; ls += p;
            }
            ls += __shfl_xor(ls, 1); ls += __shfl_xor(ls, 2);
            ls += __shfl_xor(ls, 4); ls += __shfl_xor(ls, 8);
            l[r] = alpha * l[r] + ls;
            m[r] = mn;
            #pragma unroll
            for (int df = 0; df < 4; df++) O[df][r] *= alpha;
        }
        #pragma unroll
        for (int jf = 0; jf < 4; jf++)
            #pragma unroll
            for (int r = 0; r < 4; r++)
                Pl[w][4 * g + r][jf * 16 + l15] = (f16)pj[jf][r];
        #pragma unroll
        for (int s = 0; s < 2; s++) {
            f16x8 pf = *(const f16x8*)(&Pl[w][l15][s * 32 + g * 8]);
            #pragma unroll
            for (int df = 0; df < 4; df++)
                O[df] = __builtin_amdgcn_mfma_f32_16x16x32_f16(pf, vreg[s * 4 + df], O[df], 0, 0, 0);
        }
        #pragma unroll
        for (int i = 0; i < 8; i++) kreg[i] = knext[i];
    }

    int rowbase = third * 24624 + bh * 513;
    #pragma unroll
    for (int r = 0; r < 4; r++) {
        int qi = q0w + 4 * g + r;
        if (qi > 512) continue;
        size_t ro = (size_t)(rowbase + qi);
        #pragma unroll
        for (int df = 0; df < 4; df++)
            Op[ro * 64 + df * 16 + l15] = (f16)O[df][r];
        if (l15 == 0) {
            ml[ro * 2 + 0] = m[r];
            ml[ro * 2 + 1] = l[r];
        }
    }
}

// ---------------- combine SPLITS attention partials -> ob f16 ----------------
__global__ __launch_bounds__(256) void attn_combine_kernel(
    const f16* __restrict__ Op, const float* __restrict__ ml,
    f16* __restrict__ ob)
{
    int row = blockIdx.x * 4 + (threadIdx.x >> 6);
    if (row >= 24624) return;
    int lane = threadIdx.x & 63;
    int bh = row / 513, qi = row - bh * 513;
    int b = bh / 6, h = bh - b * 6;
    float mv[SPLITS], lv[SPLITS], mm = -INFINITY;
    #pragma unroll
    for (int s = 0; s < SPLITS; s++) {
        mv[s] = ml[((size_t)s * 24624 + row) * 2];
        lv[s] = ml[((size_t)s * 24624 + row) * 2 + 1];
        mm = fmaxf(mm, mv[s]);
    }
    float onum = 0.f, lden = 0.f;
    #pragma unroll
    for (int s = 0; s < SPLITS; s++) {
        float a = (mv[s] == -INFINITY) ? 0.f : __expf(mv[s] - mm);
        lden += lv[s] * a;
        onum += (float)Op[((size_t)s * 24624 + row) * 64 + lane] * a;
    }
    ob[((size_t)(b * 513 + qi)) * 384 + h * 64 + lane] = (f16)(onum / lden);
}

// ---------------- head ----------------
__global__ __launch_bounds__(384) void head_kernel(
    const float* __restrict__ x, const float* __restrict__ lg, const float* __restrict__ lb,
    const float* __restrict__ w1, const float* __restrict__ b1,
    const float* __restrict__ w2, const float* __restrict__ b2,
    float* __restrict__ out)
{
    int b = blockIdx.x; int t = threadIdx.x;
    __shared__ float hs[384], h1[384];
    __shared__ float rs[6], rs2[6];
    const float* xp = x + (size_t)b * 513 * 384;
    float v = xp[t];
    float s = v, s2 = v * v;
    #pragma unroll
    for (int off = 32; off >= 1; off >>= 1) {
        s += __shfl_down(s, off); s2 += __shfl_down(s2, off);
    }
    if ((t & 63) == 0) { rs[t >> 6] = s; rs2[t >> 6] = s2; }
    __syncthreads();
    float S = 0.f, S2 = 0.f;
    #pragma unroll
    for (int i = 0; i < 6; i++) { S += rs[i]; S2 += rs2[i]; }
    float mu = S * (1.f / 384.f);
    float var = S2 * (1.f / 384.f) - mu * mu;
    float rstd = rsqrtf(var + EPSV);
    hs[t] = (v - mu) * rstd * lg[t] + lb[t];
    __syncthreads();
    const float* wr = w1 + (size_t)t * 384;
    float acc = b1[t];
    for (int c = 0; c < 384; c += 4) {
        float4 w4 = *reinterpret_cast<const float4*>(wr + c);
        acc += w4.x * hs[c] + w4.y * hs[c + 1] + w4.z * hs[c + 2] + w4.w * hs[c + 3];
    }
    h1[t] = gelu_f(acc);
    __syncthreads();
    float p0 = h1[t] * w2[t], p1 = h1[t] * w2[384 + t];
    #pragma unroll
    for (int off = 32; off >= 1; off >>= 1) {
        p0 += __shfl_down(p0, off); p1 += __shfl_down(p1, off);
    }
    if ((t & 63) == 0) { rs[t >> 6] = p0; rs2[t >> 6] = p1; }
    __syncthreads();
    if (t == 0) {
        float a0 = b2[0], a1 = b2[1];
        #pragma unroll
        for (int i = 0; i < 6; i++) { a0 += rs[i]; a1 += rs2[i]; }
        out[b * 2 + 0] = 1.f / (1.f + expf(-a0));
        out[b * 2 + 1] = 1.f / (1.f + expf(-a1));
    }
}

static inline int cdiv(int a, int b) { return (a + b - 1) / b; }

extern "C" void kernel_launch(void* const* d_in, const int* in_sizes, int n_in,
                              void* d_out, int out_size, void* d_ws, size_t ws_size,
                              hipStream_t stream)
{
    const float* frames  = (const float*)d_in[0];
    const float* conv1_w = (const float*)d_in[1];
    const float* bn1_g = (const float*)d_in[2]; const float* bn1_b = (const float*)d_in[3];
    const float* bn1_m = (const float*)d_in[4]; const float* bn1_v = (const float*)d_in[5];
    const float* conv2_w = (const float*)d_in[6];
    const float* bn2_g = (const float*)d_in[7]; const float* bn2_b = (const float*)d_in[8];
    const float* bn2_m = (const float*)d_in[9]; const float* bn2_v = (const float*)d_in[10];
    const float* conv3_w = (const float*)d_in[11];
    const float* bn3_g = (const float*)d_in[12]; const float* bn3_b = (const float*)d_in[13];
    const float* bn3_m = (const float*)d_in[14]; const float* bn3_v = (const float*)d_in[15];
    const float* proj_w = (const float*)d_in[16];
    const float* dw_w = (const float*)d_in[17]; const float* dw_b = (const float*)d_in[18];
    const float* pw_w = (const float*)d_in[19]; const float* pw_b = (const float*)d_in[20];
    const float* tnorm_g = (const float*)d_in[21]; const float* tnorm_b = (const float*)d_in[22];
    const float* frame_pos = (const float*)d_in[23];
    const float* patch_pos = (const float*)d_in[24];
    const float* cls_token = (const float*)d_in[25];
    const float* cls_pos = (const float*)d_in[26];
    const float* qkv_w = (const float*)d_in[27]; const float* qkv_b = (const float*)d_in[28];
    const float* out_w = (const float*)d_in[29]; const float* out_b = (const float*)d_in[30];
    const float* ln1_g = (const float*)d_in[31]; const float* ln1_b = (const float*)d_in[32];
    const float* ln2_g = (const float*)d_in[33]; const float* ln2_b = (const float*)d_in[34];
    const float* ffn_w1 = (const float*)d_in[35]; const float* ffn_b1 = (const float*)d_in[36];
    const float* ffn_w2 = (const float*)d_in[37]; const float* ffn_b2 = (const float*)d_in[38];
    const float* head_ln_g = (const float*)d_in[39]; const float* head_ln_b = (const float*)d_in[40];
    const float* head_w1 = (const float*)d_in[41]; const float* head_b1 = (const float*)d_in[42];
    const float* head_w2 = (const float*)d_in[43]; const float* head_b2 = (const float*)d_in[44];
    (void)in_sizes; (void)n_in; (void)out_size; (void)ws_size;

    char* base = (char*)d_ws;
    size_t off = 0;
    auto alloc = [&](size_t bytes) { void* p = base + off; off = (off + bytes + 255) & ~(size_t)255; return p; };

    // persistent region
    f16* wtotal = (f16*)alloc((size_t)10960896 * 2);
    f16* projw16 = wtotal;
    f16* pw16    = wtotal + 49152;
    f16* qkvw16  = wtotal + 344064;
    f16* outw16  = wtotal + 2998272;
    f16* f1w16   = wtotal + 3883008;
    f16* f2w16   = wtotal + 7421952;
    f16* c1wB    = (f16*)alloc(1024 * 2);
    f16* c2w16   = (f16*)alloc((size_t)64 * 288 * 2);
    f16* c3w16   = (f16*)alloc((size_t)128 * 576 * 2);
    f16* pooled  = (f16*)alloc((size_t)4096 * 128 * 2);
    float* tc    = (float*)alloc((size_t)4096 * 384 * 4);

    // union region: stem scratch vs mixer/transformer scratch
    size_t ustart = off;
    f16* c1h = (f16*)alloc((size_t)256 * 64 * 64 * 32 * 2);
    f16* c2h = (f16*)alloc((size_t)256 * 32 * 32 * 64 * 2);
    f16* c3h = (f16*)alloc((size_t)256 * 16 * 16 * 128 * 2);
    size_t uend_stem = off;
    off = ustart;
    float* mA = (float*)alloc((size_t)4096 * 384 * 4);
    float* mB = (float*)alloc((size_t)4096 * 384 * 4);
    f16*   mh = (f16*)alloc((size_t)4096 * 384 * 2);
    float* xb   = (float*)alloc((size_t)8 * 513 * 384 * 4);
    f16*   hb   = (f16*)alloc((size_t)8 * 513 * 384 * 2);
    f16*   qkvb = (f16*)alloc((size_t)8 * 513 * 1152 * 2);
    f16*   vTb  = (f16*)alloc((size_t)48 * 64 * 576 * 2);
    f16*   ob   = (f16*)alloc((size_t)8 * 513 * 384 * 2);
    f16*   ffb  = (f16*)alloc((size_t)8 * 513 * 1536 * 2);
    f16*   Opart = (f16*)alloc((size_t)SPLITS * 24624 * 64 * 2);
    float* mlpart = (float*)alloc((size_t)SPLITS * 24624 * 2 * 4);
    if (off < uend_stem) off = uend_stem;

    // ---------- weight conversion ----------
    cvt_all_kernel<<<4096, 256, 0, stream>>>(
        proj_w, pw_w, qkv_w, out_w, ffn_w1, ffn_w2, wtotal);
    conv1_w_prep_kernel<<<4, 256, 0, stream>>>(conv1_w, bn1_g, bn1_v, c1wB);
    conv_w_reorder_kernel<<<cdiv(64 * 288, 256), 256, 0, stream>>>(conv2_w, c2w16, 64, 32);
    conv_w_reorder_kernel<<<cdiv(128 * 576, 256), 256, 0, stream>>>(conv3_w, c3w16, 128, 64);

    // ---------- conv stem, full 256-frame batch ----------
    conv1_mfma_kernel<<<256 * 16, 256, 0, stream>>>(
        frames, c1wB, bn1_b, bn1_m, bn1_g, bn1_v, c1h);
    convg_kernel<32, 64, 64><<<dim3(4096, 1), 256, 0, stream>>>(
        c1h, c2w16, bn2_g, bn2_b, bn2_m, bn2_v, c2h);
    convg_kernel<64, 32, 128><<<dim3(1024, 2), 256, 0, stream>>>(
        c2h, c3w16, bn3_g, bn3_b, bn3_m, bn3_v, c3h);
    poolh_kernel<<<256, 256, 0, stream>>>(c3h, pooled, 256);
    // proj with TCMAP epilogue: writes directly into tc layout (b*16+p, t, d)
    gemm_k64_kernel<0, 0, 0, 1><<<384, 256, 0, stream>>>(
        pooled, projw16, nullptr, nullptr, tc, nullptr, 4096, 384, 128, 64);

    // ---------- temporal mixer (iter0 reads tc directly) ----------
    dwconv_kernel<<<cdiv(128 * 32 * 384, 256), 256, 0, stream>>>(
        tc, dw_w, dw_b, mh, 1);
    gemm_k64_kernel<0, 0, 0, 0><<<384, 256, 0, stream>>>(
        mh, pw16, pw_b, tc, mA, nullptr, 4096, 384, 384, 64);
    dwconv_kernel<<<cdiv(128 * 32 * 384, 256), 256, 0, stream>>>(
        mA, dw_w + 384 * 3, dw_b + 384, mh, 2);
    gemm_k64_kernel<0, 0, 0, 0><<<384, 256, 0, stream>>>(
        mh, pw16 + 384 * 384, pw_b + 384, mA, mB, nullptr, 4096, 384, 384, 64);

    // ---------- build transformer input x ----------
    build_x_kernel<<<128 * 32, 128, 0, stream>>>(
        mB, tc, tnorm_g, tnorm_b, frame_pos, patch_pos, xb);
    cls_kernel<<<cdiv(8 * 384, 256), 256, 0, stream>>>(cls_token, cls_pos, xb);

    // ---------- transformer ----------
    const int M = 8 * 513;        // 4104
    const int NR = cdiv(M, 64);   // 65
    for (int l = 0; l < 6; l++) {
        ln_wave_kernel<<<cdiv(M, 4), 256, 0, stream>>>(xb,
            ln1_g + (size_t)l * 384, ln1_b + (size_t)l * 384, hb, M);
        gemm_k64_kernel<1, 0, 1, 0><<<NR * 18, 256, 0, stream>>>(
            hb, qkvw16 + (size_t)l * 1152 * 384, qkv_b + (size_t)l * 1152,
            nullptr, qkvb, vTb, M, 1152, 384, NR);
        fattn_split_kernel<<<dim3(9, 48, SPLITS), 256, 0, stream>>>(qkvb, vTb, Opart, mlpart);
        attn_combine_kernel<<<cdiv(24624, 4), 256, 0, stream>>>(Opart, mlpart, ob);
        gemm_k64_kernel<0, 0, 0, 0><<<NR * 6, 256, 0, stream>>>(
            ob, outw16 + (size_t)l * 384 * 384, out_b + (size_t)l * 384,
            xb, xb, nullptr, M, 384, 384, NR);
        ln_wave_kernel<<<cdiv(M, 4), 256, 0, stream>>>(xb,
            ln2_g + (size_t)l * 384, ln2_b + (size_t)l * 384, hb, M);
        gemm_kn128_kernel<1><<<NR * 12, 256, 0, stream>>>(
            hb, f1w16 + (size_t)l * 1536 * 384, ffn_b1 + (size_t)l * 1536,
            ffb, M, 1536, 384, NR);
        gemm_k64_kernel<0, 0, 0, 0><<<NR * 6, 256, 0, stream>>>(
            ffb, f2w16 + (size_t)l * 384 * 1536, ffn_b2 + (size_t)l * 384,
            xb, xb, nullptr, M, 384, 1536, NR);
    }

    // ---------- head ----------
    head_kernel<<<8, 384, 0, stream>>>(
        xb, head_ln_g, head_ln_b, head_w1, head_b1, head_w2, head_b2, (float*)d_out);
}

// Round 13
// 834.334 us; speedup vs baseline: 1.4621x; 1.0101x over previous
//
#include <hip/hip_runtime.h>
#include <hip/hip_fp16.h>
#include <cstddef>

#define EPSV 1e-5f
#define SPLITS 4

typedef _Float16 f16;
typedef _Float16 f16x8 __attribute__((ext_vector_type(8)));
typedef float f32x4v __attribute__((ext_vector_type(4)));

__device__ __forceinline__ float gelu_f(float x) {
    return 0.5f * x * (1.0f + erff(x * 0.7071067811865476f));
}

// branch-free tanh-GELU: x*(1 - 1/(exp2(z)+1)), z = x*(2.3025851+0.10296103 x^2)
__device__ __forceinline__ float gelu_fast(float x) {
    float x2 = x * x;
    float z = x * fmaf(0.10296103f, x2, 2.3025851f);
    float e = exp2f(z);
    float r = __builtin_amdgcn_rcpf(e + 1.0f);
    return fmaf(-x, r, x);
}

// ---------------- all-weights f32 -> f16 convert (one dispatch) ----------------
__global__ __launch_bounds__(256) void cvt_all_kernel(
    const float* __restrict__ p0, const float* __restrict__ p1,
    const float* __restrict__ p2, const float* __restrict__ p3,
    const float* __restrict__ p4, const float* __restrict__ p5,
    f16* __restrict__ dst)
{
    const int n = 10960896;
    for (int i = blockIdx.x * 256 + threadIdx.x; i < n; i += gridDim.x * 256) {
        const float* s; int off;
        if      (i <   49152) { s = p0; off = i; }
        else if (i <  344064) { s = p1; off = i -   49152; }
        else if (i < 2998272) { s = p2; off = i -  344064; }
        else if (i < 3883008) { s = p3; off = i - 2998272; }
        else if (i < 7421952) { s = p4; off = i - 3883008; }
        else                  { s = p5; off = i - 7421952; }
        dst[i] = (f16)s[off];
    }
}

// ---------------- conv weight reorder ----------------
__global__ __launch_bounds__(256) void conv_w_reorder_kernel(
    const float* __restrict__ w, f16* __restrict__ out, int CO, int CI)
{
    int n = CO * CI * 9;
    for (int i = blockIdx.x * 256 + threadIdx.x; i < n; i += gridDim.x * 256) {
        int t = i % 9; int r = i / 9;
        int ci = r % CI; int co = r / CI;
        out[(size_t)co * CI * 9 + t * CI + ci] = (f16)w[i];
    }
}

// ---------------- conv1 weight prep ----------------
__global__ __launch_bounds__(256) void conv1_w_prep_kernel(
    const float* __restrict__ w, const float* __restrict__ g,
    const float* __restrict__ vr, f16* __restrict__ wB)
{
    int i = blockIdx.x * 256 + threadIdx.x;
    if (i >= 1024) return;
    int co = i >> 5, k = i & 31;
    float inv = g[co] * rsqrtf(vr[co] + EPSV);
    wB[i] = (f16)((k < 25) ? w[co * 25 + k] * inv : 0.f);
}

// ---------------- conv1: 5x5 s2 p2 via MFMA implicit GEMM, NHWC f16 (R10 version) ----------------
__global__ __launch_bounds__(256) void conv1_mfma_kernel(
    const float* __restrict__ in, const f16* __restrict__ wB,
    const float* __restrict__ bt, const float* __restrict__ mn,
    const float* __restrict__ g, const float* __restrict__ vr,
    f16* __restrict__ out)
{
    __shared__ __align__(16) f16 inpH[35 * 36 + 8];
    __shared__ __align__(16) f16 Bs[32 * 32];
    int bid = blockIdx.x;
    int n = bid >> 4; int tile = bid & 15;
    int ty0 = (tile >> 2) * 16, tx0 = (tile & 3) * 16;
    int t = threadIdx.x;
    const float* ip = in + (size_t)n * 16384;
    for (int e = t; e < 35 * 36; e += 256) {
        int r = e / 36, c = e - r * 36;
        int iy = ty0 * 2 - 2 + r, ix = tx0 * 2 - 2 + c;
        float v = ((unsigned)iy < 128u && (unsigned)ix < 128u && c < 35) ? ip[iy * 128 + ix] : 0.f;
        inpH[e] = (f16)v;
    }
    if (t < 128) {
        int row = t >> 2, seg = (t & 3) * 8;
        *(uint4*)(&Bs[row * 32 + seg]) = *(const uint4*)(wB + row * 32 + seg);
    }
    __syncthreads();
    int w = t >> 6, lane = t & 63;
    int l15 = lane & 15, gq = lane >> 4;
    f16x8 afr[4];
    #pragma unroll
    for (int i = 0; i < 4; i++) {
        int mt = 4 * w + i;
        f16 tmp[8];
        #pragma unroll
        for (int e = 0; e < 8; e++) {
            int kk = 8 * gq + e; if (kk > 24) kk = 24;
            int ky = kk / 5, kx = kk - ky * 5;
            tmp[e] = inpH[(2 * mt + ky) * 36 + 2 * l15 + kx];
        }
        afr[i] = *(f16x8*)tmp;
    }
    f16x8 bfr[2];
    bfr[0] = *(const f16x8*)(&Bs[l15 * 32 + 8 * gq]);
    bfr[1] = *(const f16x8*)(&Bs[(16 + l15) * 32 + 8 * gq]);
    f32x4v zero = {0.f, 0.f, 0.f, 0.f};
    f32x4v acc[4][2];
    #pragma unroll
    for (int i = 0; i < 4; i++) { acc[i][0] = zero; acc[i][1] = zero; }
    #pragma unroll
    for (int i = 0; i < 4; i++) {
        acc[i][0] = __builtin_amdgcn_mfma_f32_16x16x32_f16(afr[i], bfr[0], acc[i][0], 0, 0, 0);
        acc[i][1] = __builtin_amdgcn_mfma_f32_16x16x32_f16(afr[i], bfr[1], acc[i][1], 0, 0, 0);
    }
    float beta[2];
    #pragma unroll
    for (int nt = 0; nt < 2; nt++) {
        int co = nt * 16 + l15;
        float inv = g[co] * rsqrtf(vr[co] + EPSV);
        beta[nt] = bt[co] - mn[co] * inv;
    }
    #pragma unroll
    for (int i = 0; i < 4; i++) {
        int y = ty0 + 4 * w + i;
        #pragma unroll
        for (int q = 0; q < 4; q++) {
            int x = tx0 + 4 * gq + q;
            size_t ob = (((size_t)n * 64 + y) * 64 + x) * 32;
            #pragma unroll
            for (int nt = 0; nt < 2; nt++) {
                int co = nt * 16 + l15;
                out[ob + co] = (f16)gelu_fast(acc[i][nt][q] + beta[nt]);
            }
        }
    }
}

// ---------------- implicit-GEMM conv 3x3 s2 p1, NHWC f16, MFMA, reg prefetch (R10) ----------------
template<int CI, int HI, int CO>
__global__ __launch_bounds__(256) void convg_kernel(
    const f16* __restrict__ in, const f16* __restrict__ wr_,
    const float* __restrict__ g, const float* __restrict__ bt,
    const float* __restrict__ mn, const float* __restrict__ vr,
    f16* __restrict__ out)
{
    constexpr int HO = HI / 2;
    constexpr int HOB = (HO == 32) ? 5 : 4;
    constexpr int K = 9 * CI;
    __shared__ __align__(16) f16 As[64 * 40];
    __shared__ __align__(16) f16 Bs[64 * 40];
    int tid = threadIdx.x;
    int bm = blockIdx.x * 64;
    int bn = blockIdx.y * 64;
    int lrow = tid >> 2, lseg = tid & 3;
    int w = tid >> 6, lane = tid & 63;
    int wr = (w >> 1) * 32, wc = (w & 1) * 32;
    int l15 = lane & 15, l4 = lane >> 4;
    int gp = bm + lrow;
    int pn = gp >> (2 * HOB);
    int prem = gp & ((1 << (2 * HOB)) - 1);
    int oy = prem >> HOB, ox = prem & (HO - 1);

    f32x4v zero = {0.f, 0.f, 0.f, 0.f};
    f32x4v acc[2][2];
    acc[0][0] = zero; acc[0][1] = zero; acc[1][0] = zero; acc[1][1] = zero;

    auto loadTile = [&](int k0, uint4& av, uint4& bv) {
        int tap = k0 / CI;
        int cio = k0 - tap * CI;
        int ky = tap / 3, kx = tap - ky * 3;
        int iy = oy * 2 - 1 + ky, ix = ox * 2 - 1 + kx;
        av = make_uint4(0u, 0u, 0u, 0u);
        if ((unsigned)iy < (unsigned)HI && (unsigned)ix < (unsigned)HI)
            av = *(const uint4*)(in + (((size_t)(pn * HI + iy)) * HI + ix) * CI + cio + lseg * 8);
        bv = *(const uint4*)(wr_ + (size_t)(bn + lrow) * K + k0 + lseg * 8);
    };

    uint4 ra, rb;
    loadTile(0, ra, rb);
    for (int k0 = 0; k0 < K; k0 += 32) {
        __syncthreads();
        *(uint4*)(&As[lrow * 40 + lseg * 8]) = ra;
        *(uint4*)(&Bs[lrow * 40 + lseg * 8]) = rb;
        if (k0 + 32 < K) loadTile(k0 + 32, ra, rb);
        __syncthreads();
        f16x8 a0 = *(const f16x8*)(&As[(wr + l15) * 40 + l4 * 8]);
        f16x8 a1 = *(const f16x8*)(&As[(wr + 16 + l15) * 40 + l4 * 8]);
        f16x8 b0 = *(const f16x8*)(&Bs[(wc + l15) * 40 + l4 * 8]);
        f16x8 b1 = *(const f16x8*)(&Bs[(wc + 16 + l15) * 40 + l4 * 8]);
        acc[0][0] = __builtin_amdgcn_mfma_f32_16x16x32_f16(a0, b0, acc[0][0], 0, 0, 0);
        acc[0][1] = __builtin_amdgcn_mfma_f32_16x16x32_f16(a0, b1, acc[0][1], 0, 0, 0);
        acc[1][0] = __builtin_amdgcn_mfma_f32_16x16x32_f16(a1, b0, acc[1][0], 0, 0, 0);
        acc[1][1] = __builtin_amdgcn_mfma_f32_16x16x32_f16(a1, b1, acc[1][1], 0, 0, 0);
    }
    float inv[2], beta[2];
    #pragma unroll
    for (int ni = 0; ni < 2; ni++) {
        int col = bn + wc + ni * 16 + l15;
        float iv = g[col] * rsqrtf(vr[col] + EPSV);
        inv[ni] = iv; beta[ni] = bt[col] - mn[col] * iv;
    }
    #pragma unroll
    for (int mi = 0; mi < 2; mi++) {
        #pragma unroll
        for (int q = 0; q < 4; q++) {
            int pixel = bm + wr + mi * 16 + l4 * 4 + q;
            #pragma unroll
            for (int ni = 0; ni < 2; ni++) {
                int col = bn + wc + ni * 16 + l15;
                float v = acc[mi][ni][q] * inv[ni] + beta[ni];
                out[(size_t)pixel * CO + col] = (f16)gelu_fast(v);
            }
        }
    }
}

// ---------------- 4x4 avg pool NHWC f16 ----------------
__global__ __launch_bounds__(256) void poolh_kernel(
    const f16* __restrict__ in, f16* __restrict__ out, int NC)
{
    int idx = blockIdx.x * 256 + threadIdx.x;
    if (idx >= NC * 16 * 16) return;
    int cc = idx & 15; int npl = idx >> 4;
    int c0 = cc * 8;
    int n = npl >> 4; int p = npl & 15;
    int ph = p >> 2, pw = p & 3;
    const f16* base = in + (((size_t)(n * 16 + ph * 4)) * 16 + pw * 4) * 128 + c0;
    float s[8] = {};
    #pragma unroll
    for (int dy = 0; dy < 4; dy++)
        #pragma unroll
        for (int dx = 0; dx < 4; dx++) {
            f16x8 v = *(const f16x8*)(base + (dy * 16 + dx) * 128);
            #pragma unroll
            for (int u = 0; u < 8; u++) s[u] += (float)v[u];
        }
    f16* op = out + (size_t)npl * 128 + c0;
    #pragma unroll
    for (int u = 0; u < 8; u++) op[u] = (f16)(s[u] * 0.0625f);
}

// ---------------- MFMA f16 NT GEMM, 64x64 tile, BK=64, XCD-swizzled 1D grid ----------------
template<int OUTF16, int ACT, int VTRANS, int TCMAP>
__global__ __launch_bounds__(256) void gemm_k64_kernel(
    const f16* __restrict__ A, const f16* __restrict__ B,
    const float* __restrict__ bias, const float* __restrict__ res,
    void* __restrict__ Cv, f16* __restrict__ vT, int M, int N, int K, int nrow)
{
    __shared__ __align__(16) f16 As[64 * 72];
    __shared__ __align__(16) f16 Bs[64 * 72];
    int nb = gridDim.x;
    int q = nb >> 3, r = nb & 7;
    int xcd = blockIdx.x & 7, pos = blockIdx.x >> 3;
    int logical = (xcd < r ? xcd * (q + 1) : r * (q + 1) + (xcd - r) * q) + pos;
    int brow = logical % nrow, bcol = logical / nrow;
    int bm = brow * 64, bn = bcol * 64;

    int tid = threadIdx.x;
    int lrow = tid >> 2, lseg = (tid & 3) * 16;
    int w = tid >> 6, lane = tid & 63;
    int wr = (w >> 1) * 32, wc = (w & 1) * 32;
    int l15 = lane & 15, l4 = lane >> 4;
    f32x4v zero = {0.f, 0.f, 0.f, 0.f};
    f32x4v acc[2][2];
    acc[0][0] = zero; acc[0][1] = zero; acc[1][0] = zero; acc[1][1] = zero;

    int arow = bm + lrow;
    bool aok = (arow < M);
    const f16* ap = A + (size_t)arow * K + lseg;
    const f16* bp = B + (size_t)(bn + lrow) * K + lseg;

    uint4 ra0 = make_uint4(0u,0u,0u,0u), ra1 = ra0, rb0, rb1;
    if (aok) { ra0 = *(const uint4*)(ap); ra1 = *(const uint4*)(ap + 8); }
    rb0 = *(const uint4*)(bp); rb1 = *(const uint4*)(bp + 8);

    int nt = K >> 6;
    for (int t = 0; t < nt; t++) {
        __syncthreads();
        *(uint4*)(&As[lrow * 72 + lseg])     = ra0;
        *(uint4*)(&As[lrow * 72 + lseg + 8]) = ra1;
        *(uint4*)(&Bs[lrow * 72 + lseg])     = rb0;
        *(uint4*)(&Bs[lrow * 72 + lseg + 8]) = rb1;
        if (t + 1 < nt) {
            int k0 = (t + 1) << 6;
            if (aok) { ra0 = *(const uint4*)(ap + k0); ra1 = *(const uint4*)(ap + k0 + 8); }
            rb0 = *(const uint4*)(bp + k0); rb1 = *(const uint4*)(bp + k0 + 8);
        }
        __syncthreads();
        #pragma unroll
        for (int s = 0; s < 2; s++) {
            f16x8 a0 = *(const f16x8*)(&As[(wr + l15) * 72 + s * 32 + l4 * 8]);
            f16x8 a1 = *(const f16x8*)(&As[(wr + 16 + l15) * 72 + s * 32 + l4 * 8]);
            f16x8 b0 = *(const f16x8*)(&Bs[(wc + l15) * 72 + s * 32 + l4 * 8]);
            f16x8 b1 = *(const f16x8*)(&Bs[(wc + 16 + l15) * 72 + s * 32 + l4 * 8]);
            acc[0][0] = __builtin_amdgcn_mfma_f32_16x16x32_f16(a0, b0, acc[0][0], 0, 0, 0);
            acc[0][1] = __builtin_amdgcn_mfma_f32_16x16x32_f16(a0, b1, acc[0][1], 0, 0, 0);
            acc[1][0] = __builtin_amdgcn_mfma_f32_16x16x32_f16(a1, b0, acc[1][0], 0, 0, 0);
            acc[1][1] = __builtin_amdgcn_mfma_f32_16x16x32_f16(a1, b1, acc[1][1], 0, 0, 0);
        }
    }

    if (VTRANS && bn >= 768) {
        __syncthreads();
        f16* tile = As;   // [64][66]
        #pragma unroll
        for (int mi = 0; mi < 2; mi++)
            #pragma unroll
            for (int qq = 0; qq < 4; qq++) {
                int rl = wr + mi * 16 + l4 * 4 + qq;
                #pragma unroll
                for (int ni = 0; ni < 2; ni++) {
                    int dl = wc + ni * 16 + l15;
                    float v = acc[mi][ni][qq] + bias[bn + dl];
                    tile[dl * 66 + rl] = (f16)v;
                }
            }
        __syncthreads();
        int h = (bn - 768) >> 6;
        int j = tid & 63, dbase = tid >> 6;
        int trow = bm + j;
        if (trow < M) {
            int b = trow / 513;
            int jj = trow - b * 513;
            f16* vb = vT + ((size_t)(b * 6 + h) * 64) * 576 + jj;
            #pragma unroll
            for (int it = 0; it < 16; it++) {
                int d = dbase * 16 + it;
                vb[(size_t)d * 576] = tile[d * 66 + j];
            }
        }
        return;
    }
    #pragma unroll
    for (int mi = 0; mi < 2; mi++) {
        #pragma unroll
        for (int qq = 0; qq < 4; qq++) {
            int row = bm + wr + mi * 16 + l4 * 4 + qq;
            if (row >= M) continue;
            #pragma unroll
            for (int ni = 0; ni < 2; ni++) {
                int col = bn + wc + ni * 16 + l15;
                float v = acc[mi][ni][qq];
                if (bias) v += bias[col];
                if (ACT == 1) v = gelu_fast(v);
                if (res) v += res[(size_t)row * N + col];
                int orow = row;
                if (TCMAP) orow = (row & ~511) | ((row & 15) << 5) | ((row >> 4) & 31);
                if (OUTF16) ((f16*)Cv)[(size_t)orow * N + col] = (f16)v;
                else ((float*)Cv)[(size_t)orow * N + col] = v;
            }
        }
    }
}

// ---------------- MFMA f16 NT GEMM, 64x128 tile (wave 32x64), BK=64 ----------------
template<int ACT>
__global__ __launch_bounds__(256) void gemm_kn128_kernel(
    const f16* __restrict__ A, const f16* __restrict__ B,
    const float* __restrict__ bias, f16* __restrict__ C,
    int M, int N, int K, int nrow)
{
    __shared__ __align__(16) f16 As[64 * 72];
    __shared__ __align__(16) f16 Bs[128 * 72];
    int nb = gridDim.x;
    int q = nb >> 3, r = nb & 7;
    int xcd = blockIdx.x & 7, pos = blockIdx.x >> 3;
    int logical = (xcd < r ? xcd * (q + 1) : r * (q + 1) + (xcd - r) * q) + pos;
    int brow = logical % nrow, bcol = logical / nrow;
    int bm = brow * 64, bn = bcol * 128;

    int tid = threadIdx.x;
    int w = tid >> 6, lane = tid & 63;
    int wr = (w >> 1) * 32, wc = (w & 1) * 64;
    int l15 = lane & 15, l4 = lane >> 4;
    int alrow = tid >> 2, alseg = (tid & 3) * 16;
    int blrow = tid >> 1, blseg = (tid & 1) * 32;

    f32x4v zero = {0.f, 0.f, 0.f, 0.f};
    f32x4v acc[2][4];
    #pragma unroll
    for (int i = 0; i < 2; i++)
        #pragma unroll
        for (int j = 0; j < 4; j++) acc[i][j] = zero;

    int arow = bm + alrow;
    bool aok = (arow < M);
    const f16* ap = A + (size_t)arow * K + alseg;
    const f16* bp = B + (size_t)(bn + blrow) * K + blseg;

    uint4 ra0 = make_uint4(0u,0u,0u,0u), ra1 = ra0;
    uint4 rb0, rb1, rb2, rb3;
    if (aok) { ra0 = *(const uint4*)(ap); ra1 = *(const uint4*)(ap + 8); }
    rb0 = *(const uint4*)(bp);      rb1 = *(const uint4*)(bp + 8);
    rb2 = *(const uint4*)(bp + 16); rb3 = *(const uint4*)(bp + 24);

    int ntiles = K >> 6;
    for (int t = 0; t < ntiles; t++) {
        __syncthreads();
        *(uint4*)(&As[alrow * 72 + alseg])     = ra0;
        *(uint4*)(&As[alrow * 72 + alseg + 8]) = ra1;
        *(uint4*)(&Bs[blrow * 72 + blseg])      = rb0;
        *(uint4*)(&Bs[blrow * 72 + blseg + 8])  = rb1;
        *(uint4*)(&Bs[blrow * 72 + blseg + 16]) = rb2;
        *(uint4*)(&Bs[blrow * 72 + blseg + 24]) = rb3;
        if (t + 1 < ntiles) {
            int k0 = (t + 1) << 6;
            if (aok) { ra0 = *(const uint4*)(ap + k0); ra1 = *(const uint4*)(ap + k0 + 8); }
            rb0 = *(const uint4*)(bp + k0);      rb1 = *(const uint4*)(bp + k0 + 8);
            rb2 = *(const uint4*)(bp + k0 + 16); rb3 = *(const uint4*)(bp + k0 + 24);
        }
        __syncthreads();
        #pragma unroll
        for (int s = 0; s < 2; s++) {
            f16x8 a0 = *(const f16x8*)(&As[(wr + l15) * 72 + s * 32 + l4 * 8]);
            f16x8 a1 = *(const f16x8*)(&As[(wr + 16 + l15) * 72 + s * 32 + l4 * 8]);
            #pragma unroll
            for (int j = 0; j < 4; j++) {
                f16x8 bf = *(const f16x8*)(&Bs[(wc + j * 16 + l15) * 72 + s * 32 + l4 * 8]);
                acc[0][j] = __builtin_amdgcn_mfma_f32_16x16x32_f16(a0, bf, acc[0][j], 0, 0, 0);
                acc[1][j] = __builtin_amdgcn_mfma_f32_16x16x32_f16(a1, bf, acc[1][j], 0, 0, 0);
            }
        }
    }
    #pragma unroll
    for (int mi = 0; mi < 2; mi++) {
        #pragma unroll
        for (int qq = 0; qq < 4; qq++) {
            int row = bm + wr + mi * 16 + l4 * 4 + qq;
            if (row >= M) continue;
            #pragma unroll
            for (int j = 0; j < 4; j++) {
                int col = bn + wc + j * 16 + l15;
                float v = acc[mi][j][qq];
                if (bias) v += bias[col];
                if (ACT == 1) v = gelu_fast(v);
                C[(size_t)row * N + col] = (f16)v;
            }
        }
    }
}

// ---------------- depthwise temporal conv, 4 ch/thread, float4 taps -> f16 ----------------
__global__ __launch_bounds__(256) void dwconv_kernel(
    const float* __restrict__ in, const float* __restrict__ w,
    const float* __restrict__ bias, f16* __restrict__ out, int dil)
{
    int idx = blockIdx.x * 256 + threadIdx.x;
    if (idx >= 128 * 32 * 96) return;
    int dg = idx % 96; int t = (idx / 96) & 31; int s = idx / (96 * 32);
    int d = dg * 4;
    const float* ip = in + (size_t)s * 32 * 384 + d;
    float4 acc = *(const float4*)(bias + d);
    #pragma unroll
    for (int k = 0; k < 3; k++) {
        int tt = t + (k - 1) * dil;
        if ((unsigned)tt < 32u) {
            float4 v = *(const float4*)(ip + tt * 384);
            acc.x = fmaf(w[(d + 0) * 3 + k], v.x, acc.x);
            acc.y = fmaf(w[(d + 1) * 3 + k], v.y, acc.y);
            acc.z = fmaf(w[(d + 2) * 3 + k], v.z, acc.z);
            acc.w = fmaf(w[(d + 3) * 3 + k], v.w, acc.w);
        }
    }
    f16 o[4];
    o[0] = (f16)gelu_fast(acc.x); o[1] = (f16)gelu_fast(acc.y);
    o[2] = (f16)gelu_fast(acc.z); o[3] = (f16)gelu_fast(acc.w);
    *(uint2*)(out + ((size_t)(s * 32 + t) * 384 + d)) = *(uint2*)o;
}

// ---------------- LayerNorm: wave-per-row, shfl reduce, f32 in -> f16 out ----------------
__global__ __launch_bounds__(256) void ln_wave_kernel(
    const float* __restrict__ in,
    const float* __restrict__ g, const float* __restrict__ b,
    f16* __restrict__ out, int rows)
{
    int w = threadIdx.x >> 6, lane = threadIdx.x & 63;
    int row = blockIdx.x * 4 + w;
    if (row >= rows) return;
    const float* ip = in + (size_t)row * 384;
    float x[6]; float s = 0.f, s2 = 0.f;
    #pragma unroll
    for (int k = 0; k < 6; k++) {
        float v = ip[lane + 64 * k];
        x[k] = v; s += v; s2 += v * v;
    }
    #pragma unroll
    for (int off = 1; off < 64; off <<= 1) {
        s += __shfl_xor(s, off); s2 += __shfl_xor(s2, off);
    }
    float mu = s * (1.f / 384.f);
    float var = s2 * (1.f / 384.f) - mu * mu;
    float rs = rsqrtf(var + EPSV);
    #pragma unroll
    for (int k = 0; k < 6; k++) {
        int c = lane + 64 * k;
        out[(size_t)row * 384 + c] = (f16)((x[k] - mu) * rs * g[c] + b[c]);
    }
}

// ---------------- mixer-final LN + positional add ----------------
__global__ __launch_bounds__(128) void build_x_kernel(
    const float* __restrict__ mix, const float* __restrict__ tc,
    const float* __restrict__ tg, const float* __restrict__ tb,
    const float* __restrict__ fpos, const float* __restrict__ ppos,
    float* __restrict__ x)
{
    int row = blockIdx.x;
    int t = row & 31; int bp = row >> 5;
    int p = bp & 15; int b = bp >> 4;
    int tid = threadIdx.x;
    const float* ip = mix + (size_t)row * 384;
    const float* ip2 = tc + (size_t)row * 384;
    __shared__ float red[128], red2[128];
    float v[3]; float s = 0.f, s2 = 0.f;
    #pragma unroll
    for (int j = 0; j < 3; j++) {
        float val = ip[tid + 128 * j] + ip2[tid + 128 * j];
        v[j] = val; s += val; s2 += val * val;
    }
    red[tid] = s; red2[tid] = s2; __syncthreads();
    for (int off = 64; off >= 1; off >>= 1) {
        if (tid < off) { red[tid] += red[tid + off]; red2[tid] += red2[tid + off]; }
        __syncthreads();
    }
    float mu = red[0] * (1.f / 384.f);
    float var = red2[0] * (1.f / 384.f) - mu * mu;
    float rs = rsqrtf(var + EPSV);
    size_t xbase = ((size_t)b * 513 + 1 + t * 16 + p) * 384;
    #pragma unroll
    for (int j = 0; j < 3; j++) {
        int c = tid + 128 * j;
        float y = (v[j] - mu) * rs * tg[c] + tb[c] + fpos[t * 384 + c] + ppos[p * 384 + c];
        x[xbase + c] = y;
    }
}

__global__ __launch_bounds__(256) void cls_kernel(
    const float* __restrict__ ct, const float* __restrict__ cp, float* __restrict__ x)
{
    int idx = blockIdx.x * 256 + threadIdx.x;
    if (idx >= 8 * 384) return;
    int c = idx % 384; int b = idx / 384;
    x[(size_t)b * 513 * 384 + c] = ct[c] + cp[c];
}

// ---------------- flash attention, SPLITS-way j-split + K/V register prefetch ----------------
__global__ __launch_bounds__(256) void fattn_split_kernel(
    const f16* __restrict__ qkv, const f16* __restrict__ vT,
    f16* __restrict__ Op, float* __restrict__ ml)
{
    __shared__ __align__(16) f16 Pl[4][16][72];
    int qt = blockIdx.x;
    int bh = blockIdx.y; int h = bh % 6; int b = bh / 6;
    int third = blockIdx.z;
    int tid = threadIdx.x;
    int w = tid >> 6, lane = tid & 63;
    int l15 = lane & 15, g = lane >> 4;
    int q0w = qt * 64 + w * 16;
    if (q0w > 512) return;
    const size_t RS = 1152;
    const f16* qbase = qkv + (size_t)b * 513 * RS + h * 64;
    const f16* kbase = qbase + 384;
    const f16* vtb = vT + (size_t)bh * 64 * 576;

    f16x8 qf[2];
    {
        int qrow = q0w + l15; if (qrow > 512) qrow = 512;
        const f16* qp = qbase + (size_t)qrow * RS + g * 8;
        qf[0] = *(const f16x8*)(qp);
        qf[1] = *(const f16x8*)(qp + 32);
    }

    f32x4v zero = {0.f, 0.f, 0.f, 0.f};
    f32x4v O[4]; float m[4], l[4];
    #pragma unroll
    for (int i = 0; i < 4; i++) { O[i] = zero; m[i] = -INFINITY; l[i] = 0.f; }

    int jt0 = 0;
    if (q0w > 0) { int fmin = (q0w - 1) >> 4; jt0 = (fmin * 16 + 1) >> 6; }

    int jrow[4];
    #pragma unroll
    for (int jf = 0; jf < 4; jf++) jrow[jf] = jf * 16 + l15;

    auto loadK = [&](int j0, f16x8* kr) {
        #pragma unroll
        for (int s = 0; s < 2; s++)
            #pragma unroll
            for (int jf = 0; jf < 4; jf++) {
                int j = j0 + jrow[jf]; if (j > 512) j = 512;
                kr[s * 4 + jf] = *(const f16x8*)(kbase + (size_t)j * RS + s * 32 + g * 8);
            }
    };

    int jt = jt0 + third;
    f16x8 kreg[8];
    if (jt < 9) loadK(jt * 64, kreg);

    for (; jt < 9; jt += SPLITS) {
        int j0 = jt * 64;
        f16x8 vreg[8];
        #pragma unroll
        for (int s = 0; s < 2; s++)
            #pragma unroll
            for (int df = 0; df < 4; df++)
                vreg[s * 4 + df] = *(const f16x8*)(vtb + (size_t)(df * 16 + l15) * 576 + j0 + s * 32 + g * 8);
        f32x4v S[4];
        #pragma unroll
        for (int jf = 0; jf < 4; jf++) S[jf] = zero;
        #pragma unroll
        for (int s = 0; s < 2; s++)
            #pragma unroll
            for (int jf = 0; jf < 4; jf++)
                S[jf] = __builtin_amdgcn_mfma_f32_16x16x32_f16(qf[s], kreg[s * 4 + jf], S[jf], 0, 0, 0);
        f16x8 knext[8];
        if (jt + SPLITS < 9) loadK((jt + SPLITS) * 64, knext);
        float pj[4][4];
        #pragma unroll
        for (int r = 0; r < 4; r++) {
            int qi = q0w + 4 * g + r;
            int fi = (qi == 0) ? -1 : ((qi - 1) >> 4);
            float mx = -INFINITY;
            #pragma unroll
            for (int jf = 0; jf < 4; jf++) {
                int j = j0 + jrow[jf];
                bool valid = (qi < 513) && (j < 513) &&
                             !((qi != 0) && ((j == 0) || (((j - 1) >> 4) < fi)));
                float sv = valid ? S[jf][r] * 0.125f : -INFINITY;
                pj[jf][r] = sv;
                mx = fmaxf(mx, sv);
            }
            mx = fmaxf(mx, __shfl_xor(mx, 1));
            mx = fmaxf(mx, __shfl_xor(mx, 2));
            mx = fmaxf(mx, __shfl_xor(mx, 4));
            mx = fmaxf(mx, __shfl_xor(mx, 8));
            float mn = fmaxf(m[r], mx);
            float alpha = (m[r] == -INFINITY) ? 0.f : __expf(m[r] - mn);
            float ls = 0.f;
            #pragma unroll
            for (int jf = 0; jf < 4; jf++) {
                float p = (pj[jf][r] == -INFINITY) ? 0.f : __expf(pj[jf][r] - mn);
                pj[jf][r] = p; ls += p;
            }
            ls += __shfl_xor(ls, 1); ls += __shfl_xor(ls, 2);
            ls += __shfl_xor(ls, 4); ls += __shfl_xor(ls, 8);
            l[r] = alpha * l[r] + ls;
            m[r] = mn;
            #pragma unroll
            for (int df = 0; df < 4; df++) O[df][r] *= alpha;
        }
        #pragma unroll
        for (int jf = 0; jf < 4; jf++)
            #pragma unroll
            for (int r = 0; r < 4; r++)
                Pl[w][4 * g + r][jf * 16 + l15] = (f16)pj[jf][r];
        #pragma unroll
        for (int s = 0; s < 2; s++) {
            f16x8 pf = *(const f16x8*)(&Pl[w][l15][s * 32 + g * 8]);
            #pragma unroll
            for (int df = 0; df < 4; df++)
                O[df] = __builtin_amdgcn_mfma_f32_16x16x32_f16(pf, vreg[s * 4 + df], O[df], 0, 0, 0);
        }
        #pragma unroll
        for (int i = 0; i < 8; i++) kreg[i] = knext[i];
    }

    int rowbase = third * 24624 + bh * 513;
    #pragma unroll
    for (int r = 0; r < 4; r++) {
        int qi = q0w + 4 * g + r;
        if (qi > 512) continue;
        size_t ro = (size_t)(rowbase + qi);
        #pragma unroll
        for (int df = 0; df < 4; df++)
            Op[ro * 64 + df * 16 + l15] = (f16)O[df][r];
        if (l15 == 0) {
            ml[ro * 2 + 0] = m[r];
            ml[ro * 2 + 1] = l[r];
        }
    }
}

// ---------------- combine SPLITS attention partials -> ob f16 ----------------
__global__ __launch_bounds__(256) void attn_combine_kernel(
    const f16* __restrict__ Op, const float* __restrict__ ml,
    f16* __restrict__ ob)
{
    int row = blockIdx.x * 4 + (threadIdx.x >> 6);
    if (row >= 24624) return;
    int lane = threadIdx.x & 63;
    int bh = row / 513, qi = row - bh * 513;
    int b = bh / 6, h = bh - b * 6;
    float mv[SPLITS], lv[SPLITS], mm = -INFINITY;
    #pragma unroll
    for (int s = 0; s < SPLITS; s++) {
        mv[s] = ml[((size_t)s * 24624 + row) * 2];
        lv[s] = ml[((size_t)s * 24624 + row) * 2 + 1];
        mm = fmaxf(mm, mv[s]);
    }
    float onum = 0.f, lden = 0.f;
    #pragma unroll
    for (int s = 0; s < SPLITS; s++) {
        float a = (mv[s] == -INFINITY) ? 0.f : __expf(mv[s] - mm);
        lden += lv[s] * a;
        onum += (float)Op[((size_t)s * 24624 + row) * 64 + lane] * a;
    }
    ob[((size_t)(b * 513 + qi)) * 384 + h * 64 + lane] = (f16)(onum / lden);
}

// ---------------- head ----------------
__global__ __launch_bounds__(384) void head_kernel(
    const float* __restrict__ x, const float* __restrict__ lg, const float* __restrict__ lb,
    const float* __restrict__ w1, const float* __restrict__ b1,
    const float* __restrict__ w2, const float* __restrict__ b2,
    float* __restrict__ out)
{
    int b = blockIdx.x; int t = threadIdx.x;
    __shared__ float hs[384], h1[384];
    __shared__ float rs[6], rs2[6];
    const float* xp = x + (size_t)b * 513 * 384;
    float v = xp[t];
    float s = v, s2 = v * v;
    #pragma unroll
    for (int off = 32; off >= 1; off >>= 1) {
        s += __shfl_down(s, off); s2 += __shfl_down(s2, off);
    }
    if ((t & 63) == 0) { rs[t >> 6] = s; rs2[t >> 6] = s2; }
    __syncthreads();
    float S = 0.f, S2 = 0.f;
    #pragma unroll
    for (int i = 0; i < 6; i++) { S += rs[i]; S2 += rs2[i]; }
    float mu = S * (1.f / 384.f);
    float var = S2 * (1.f / 384.f) - mu * mu;
    float rstd = rsqrtf(var + EPSV);
    hs[t] = (v - mu) * rstd * lg[t] + lb[t];
    __syncthreads();
    const float* wr = w1 + (size_t)t * 384;
    float acc = b1[t];
    for (int c = 0; c < 384; c += 4) {
        float4 w4 = *reinterpret_cast<const float4*>(wr + c);
        acc += w4.x * hs[c] + w4.y * hs[c + 1] + w4.z * hs[c + 2] + w4.w * hs[c + 3];
    }
    h1[t] = gelu_f(acc);
    __syncthreads();
    float p0 = h1[t] * w2[t], p1 = h1[t] * w2[384 + t];
    #pragma unroll
    for (int off = 32; off >= 1; off >>= 1) {
        p0 += __shfl_down(p0, off); p1 += __shfl_down(p1, off);
    }
    if ((t & 63) == 0) { rs[t >> 6] = p0; rs2[t >> 6] = p1; }
    __syncthreads();
    if (t == 0) {
        float a0 = b2[0], a1 = b2[1];
        #pragma unroll
        for (int i = 0; i < 6; i++) { a0 += rs[i]; a1 += rs2[i]; }
        out[b * 2 + 0] = 1.f / (1.f + expf(-a0));
        out[b * 2 + 1] = 1.f / (1.f + expf(-a1));
    }
}

static inline int cdiv(int a, int b) { return (a + b - 1) / b; }

extern "C" void kernel_launch(void* const* d_in, const int* in_sizes, int n_in,
                              void* d_out, int out_size, void* d_ws, size_t ws_size,
                              hipStream_t stream)
{
    const float* frames  = (const float*)d_in[0];
    const float* conv1_w = (const float*)d_in[1];
    const float* bn1_g = (const float*)d_in[2]; const float* bn1_b = (const float*)d_in[3];
    const float* bn1_m = (const float*)d_in[4]; const float* bn1_v = (const float*)d_in[5];
    const float* conv2_w = (const float*)d_in[6];
    const float* bn2_g = (const float*)d_in[7]; const float* bn2_b = (const float*)d_in[8];
    const float* bn2_m = (const float*)d_in[9]; const float* bn2_v = (const float*)d_in[10];
    const float* conv3_w = (const float*)d_in[11];
    const float* bn3_g = (const float*)d_in[12]; const float* bn3_b = (const float*)d_in[13];
    const float* bn3_m = (const float*)d_in[14]; const float* bn3_v = (const float*)d_in[15];
    const float* proj_w = (const float*)d_in[16];
    const float* dw_w = (const float*)d_in[17]; const float* dw_b = (const float*)d_in[18];
    const float* pw_w = (const float*)d_in[19]; const float* pw_b = (const float*)d_in[20];
    const float* tnorm_g = (const float*)d_in[21]; const float* tnorm_b = (const float*)d_in[22];
    const float* frame_pos = (const float*)d_in[23];
    const float* patch_pos = (const float*)d_in[24];
    const float* cls_token = (const float*)d_in[25];
    const float* cls_pos = (const float*)d_in[26];
    const float* qkv_w = (const float*)d_in[27]; const float* qkv_b = (const float*)d_in[28];
    const float* out_w = (const float*)d_in[29]; const float* out_b = (const float*)d_in[30];
    const float* ln1_g = (const float*)d_in[31]; const float* ln1_b = (const float*)d_in[32];
    const float* ln2_g = (const float*)d_in[33]; const float* ln2_b = (const float*)d_in[34];
    const float* ffn_w1 = (const float*)d_in[35]; const float* ffn_b1 = (const float*)d_in[36];
    const float* ffn_w2 = (const float*)d_in[37]; const float* ffn_b2 = (const float*)d_in[38];
    const float* head_ln_g = (const float*)d_in[39]; const float* head_ln_b = (const float*)d_in[40];
    const float* head_w1 = (const float*)d_in[41]; const float* head_b1 = (const float*)d_in[42];
    const float* head_w2 = (const float*)d_in[43]; const float* head_b2 = (const float*)d_in[44];
    (void)in_sizes; (void)n_in; (void)out_size; (void)ws_size;

    char* base = (char*)d_ws;
    size_t off = 0;
    auto alloc = [&](size_t bytes) { void* p = base + off; off = (off + bytes + 255) & ~(size_t)255; return p; };

    // persistent region
    f16* wtotal = (f16*)alloc((size_t)10960896 * 2);
    f16* projw16 = wtotal;
    f16* pw16    = wtotal + 49152;
    f16* qkvw16  = wtotal + 344064;
    f16* outw16  = wtotal + 2998272;
    f16* f1w16   = wtotal + 3883008;
    f16* f2w16   = wtotal + 7421952;
    f16* c1wB    = (f16*)alloc(1024 * 2);
    f16* c2w16   = (f16*)alloc((size_t)64 * 288 * 2);
    f16* c3w16   = (f16*)alloc((size_t)128 * 576 * 2);
    f16* pooled  = (f16*)alloc((size_t)4096 * 128 * 2);
    float* tc    = (float*)alloc((size_t)4096 * 384 * 4);

    // union region: stem scratch vs mixer/transformer scratch
    size_t ustart = off;
    f16* c1h = (f16*)alloc((size_t)256 * 64 * 64 * 32 * 2);
    f16* c2h = (f16*)alloc((size_t)256 * 32 * 32 * 64 * 2);
    f16* c3h = (f16*)alloc((size_t)256 * 16 * 16 * 128 * 2);
    size_t uend_stem = off;
    off = ustart;
    float* mA = (float*)alloc((size_t)4096 * 384 * 4);
    float* mB = (float*)alloc((size_t)4096 * 384 * 4);
    f16*   mh = (f16*)alloc((size_t)4096 * 384 * 2);
    float* xb   = (float*)alloc((size_t)8 * 513 * 384 * 4);
    f16*   hb   = (f16*)alloc((size_t)8 * 513 * 384 * 2);
    f16*   qkvb = (f16*)alloc((size_t)8 * 513 * 1152 * 2);
    f16*   vTb  = (f16*)alloc((size_t)48 * 64 * 576 * 2);
    f16*   ob   = (f16*)alloc((size_t)8 * 513 * 384 * 2);
    f16*   ffb  = (f16*)alloc((size_t)8 * 513 * 1536 * 2);
    f16*   Opart = (f16*)alloc((size_t)SPLITS * 24624 * 64 * 2);
    float* mlpart = (float*)alloc((size_t)SPLITS * 24624 * 2 * 4);
    if (off < uend_stem) off = uend_stem;

    // ---------- weight conversion ----------
    cvt_all_kernel<<<4096, 256, 0, stream>>>(
        proj_w, pw_w, qkv_w, out_w, ffn_w1, ffn_w2, wtotal);
    conv1_w_prep_kernel<<<4, 256, 0, stream>>>(conv1_w, bn1_g, bn1_v, c1wB);
    conv_w_reorder_kernel<<<cdiv(64 * 288, 256), 256, 0, stream>>>(conv2_w, c2w16, 64, 32);
    conv_w_reorder_kernel<<<cdiv(128 * 576, 256), 256, 0, stream>>>(conv3_w, c3w16, 128, 64);

    // ---------- conv stem, full 256-frame batch ----------
    conv1_mfma_kernel<<<256 * 16, 256, 0, stream>>>(
        frames, c1wB, bn1_b, bn1_m, bn1_g, bn1_v, c1h);
    convg_kernel<32, 64, 64><<<dim3(4096, 1), 256, 0, stream>>>(
        c1h, c2w16, bn2_g, bn2_b, bn2_m, bn2_v, c2h);
    convg_kernel<64, 32, 128><<<dim3(1024, 2), 256, 0, stream>>>(
        c2h, c3w16, bn3_g, bn3_b, bn3_m, bn3_v, c3h);
    poolh_kernel<<<256, 256, 0, stream>>>(c3h, pooled, 256);
    // proj with TCMAP epilogue: writes directly into tc layout (b*16+p, t, d)
    gemm_k64_kernel<0, 0, 0, 1><<<384, 256, 0, stream>>>(
        pooled, projw16, nullptr, nullptr, tc, nullptr, 4096, 384, 128, 64);

    // ---------- temporal mixer (iter0 reads tc directly) ----------
    dwconv_kernel<<<cdiv(128 * 32 * 96, 256), 256, 0, stream>>>(
        tc, dw_w, dw_b, mh, 1);
    gemm_k64_kernel<0, 0, 0, 0><<<384, 256, 0, stream>>>(
        mh, pw16, pw_b, tc, mA, nullptr, 4096, 384, 384, 64);
    dwconv_kernel<<<cdiv(128 * 32 * 96, 256), 256, 0, stream>>>(
        mA, dw_w + 384 * 3, dw_b + 384, mh, 2);
    gemm_k64_kernel<0, 0, 0, 0><<<384, 256, 0, stream>>>(
        mh, pw16 + 384 * 384, pw_b + 384, mA, mB, nullptr, 4096, 384, 384, 64);

    // ---------- build transformer input x ----------
    build_x_kernel<<<128 * 32, 128, 0, stream>>>(
        mB, tc, tnorm_g, tnorm_b, frame_pos, patch_pos, xb);
    cls_kernel<<<cdiv(8 * 384, 256), 256, 0, stream>>>(cls_token, cls_pos, xb);

    // ---------- transformer ----------
    const int M = 8 * 513;        // 4104
    const int NR = cdiv(M, 64);   // 65
    for (int l = 0; l < 6; l++) {
        ln_wave_kernel<<<cdiv(M, 4), 256, 0, stream>>>(xb,
            ln1_g + (size_t)l * 384, ln1_b + (size_t)l * 384, hb, M);
        gemm_k64_kernel<1, 0, 1, 0><<<NR * 18, 256, 0, stream>>>(
            hb, qkvw16 + (size_t)l * 1152 * 384, qkv_b + (size_t)l * 1152,
            nullptr, qkvb, vTb, M, 1152, 384, NR);
        fattn_split_kernel<<<dim3(9, 48, SPLITS), 256, 0, stream>>>(qkvb, vTb, Opart, mlpart);
        attn_combine_kernel<<<cdiv(24624, 4), 256, 0, stream>>>(Opart, mlpart, ob);
        gemm_k64_kernel<0, 0, 0, 0><<<NR * 6, 256, 0, stream>>>(
            ob, outw16 + (size_t)l * 384 * 384, out_b + (size_t)l * 384,
            xb, xb, nullptr, M, 384, 384, NR);
        ln_wave_kernel<<<cdiv(M, 4), 256, 0, stream>>>(xb,
            ln2_g + (size_t)l * 384, ln2_b + (size_t)l * 384, hb, M);
        gemm_kn128_kernel<1><<<NR * 12, 256, 0, stream>>>(
            hb, f1w16 + (size_t)l * 1536 * 384, ffn_b1 + (size_t)l * 1536,
            ffb, M, 1536, 384, NR);
        gemm_k64_kernel<0, 0, 0, 0><<<NR * 6, 256, 0, stream>>>(
            ffb, f2w16 + (size_t)l * 384 * 1536, ffn_b2 + (size_t)l * 384,
            xb, xb, nullptr, M, 384, 1536, NR);
    }

    // ---------- head ----------
    head_kernel<<<8, 384, 0, stream>>>(
        xb, head_ln_g, head_ln_b, head_w1, head_b1, head_w2, head_b2, (float*)d_out);
}

// Round 14
// 830.063 us; speedup vs baseline: 1.4696x; 1.0051x over previous
//
#include <hip/hip_runtime.h>
#include <hip/hip_fp16.h>
#include <cstddef>

#define EPSV 1e-5f
#define SPLITS 4

typedef _Float16 f16;
typedef _Float16 f16x8 __attribute__((ext_vector_type(8)));
typedef float f32x4v __attribute__((ext_vector_type(4)));

__device__ __forceinline__ float gelu_f(float x) {
    return 0.5f * x * (1.0f + erff(x * 0.7071067811865476f));
}

// branch-free tanh-GELU
__device__ __forceinline__ float gelu_fast(float x) {
    float x2 = x * x;
    float z = x * fmaf(0.10296103f, x2, 2.3025851f);
    float e = exp2f(z);
    float r = __builtin_amdgcn_rcpf(e + 1.0f);
    return fmaf(-x, r, x);
}

// ---------------- one-dispatch prep: all weight cvt + conv preps ----------------
__global__ __launch_bounds__(256) void prep_all_kernel(
    const float* __restrict__ p0, const float* __restrict__ p1,
    const float* __restrict__ p2, const float* __restrict__ p3,
    const float* __restrict__ p4, const float* __restrict__ p5,
    f16* __restrict__ dst,
    const float* __restrict__ c1w, const float* __restrict__ bn1g,
    const float* __restrict__ bn1v, f16* __restrict__ c1wB,
    const float* __restrict__ c2w, f16* __restrict__ c2o,
    const float* __restrict__ c3w, f16* __restrict__ c3o)
{
    const int n0 = 10960896;
    const int n1 = n0 + 1024;
    const int n2 = n1 + 64 * 288;
    const int n3 = n2 + 128 * 576;
    for (int i = blockIdx.x * 256 + threadIdx.x; i < n3; i += gridDim.x * 256) {
        if (i < n0) {
            const float* s; int off;
            if      (i <   49152) { s = p0; off = i; }
            else if (i <  344064) { s = p1; off = i -   49152; }
            else if (i < 2998272) { s = p2; off = i -  344064; }
            else if (i < 3883008) { s = p3; off = i - 2998272; }
            else if (i < 7421952) { s = p4; off = i - 3883008; }
            else                  { s = p5; off = i - 7421952; }
            dst[i] = (f16)s[off];
        } else if (i < n1) {
            int j = i - n0;
            int r = j >> 5, k = j & 31;
            int co = ((r & 15) << 1) | (r >> 4);   // interleaved co-pair order
            float inv = bn1g[co] * rsqrtf(bn1v[co] + EPSV);
            c1wB[j] = (f16)((k < 25) ? c1w[co * 25 + k] * inv : 0.f);
        } else if (i < n2) {
            int j = i - n1;
            int t = j % 9; int r = j / 9;
            int ci = r % 32; int co = r / 32;
            c2o[(size_t)co * 288 + t * 32 + ci] = (f16)c2w[j];
        } else {
            int j = i - n2;
            int t = j % 9; int r = j / 9;
            int ci = r % 64; int co = r / 64;
            c3o[(size_t)co * 576 + t * 64 + ci] = (f16)c3w[j];
        }
    }
}

// ---------------- conv1: 5x5 s2 p2 via MFMA implicit GEMM, co-pair packed stores ----------------
__global__ __launch_bounds__(256) void conv1_mfma_kernel(
    const float* __restrict__ in, const f16* __restrict__ wB,
    const float* __restrict__ bt, const float* __restrict__ mn,
    const float* __restrict__ g, const float* __restrict__ vr,
    f16* __restrict__ out)
{
    __shared__ __align__(16) f16 inpH[35 * 36 + 8];
    __shared__ __align__(16) f16 Bs[32 * 32];
    int bid = blockIdx.x;
    int n = bid >> 4; int tile = bid & 15;
    int ty0 = (tile >> 2) * 16, tx0 = (tile & 3) * 16;
    int t = threadIdx.x;
    const float* ip = in + (size_t)n * 16384;
    for (int e = t; e < 35 * 36; e += 256) {
        int r = e / 36, c = e - r * 36;
        int iy = ty0 * 2 - 2 + r, ix = tx0 * 2 - 2 + c;
        float v = ((unsigned)iy < 128u && (unsigned)ix < 128u && c < 35) ? ip[iy * 128 + ix] : 0.f;
        inpH[e] = (f16)v;
    }
    if (t < 128) {
        int row = t >> 2, seg = (t & 3) * 8;
        *(uint4*)(&Bs[row * 32 + seg]) = *(const uint4*)(wB + row * 32 + seg);
    }
    __syncthreads();
    int w = t >> 6, lane = t & 63;
    int l15 = lane & 15, gq = lane >> 4;
    f16x8 afr[4];
    #pragma unroll
    for (int i = 0; i < 4; i++) {
        int mt = 4 * w + i;
        f16 tmp[8];
        #pragma unroll
        for (int e = 0; e < 8; e++) {
            int kk = 8 * gq + e; if (kk > 24) kk = 24;
            int ky = kk / 5, kx = kk - ky * 5;
            tmp[e] = inpH[(2 * mt + ky) * 36 + 2 * l15 + kx];
        }
        afr[i] = *(f16x8*)tmp;
    }
    f16x8 bfr[2];
    bfr[0] = *(const f16x8*)(&Bs[l15 * 32 + 8 * gq]);
    bfr[1] = *(const f16x8*)(&Bs[(16 + l15) * 32 + 8 * gq]);
    f32x4v zero = {0.f, 0.f, 0.f, 0.f};
    f32x4v acc[4][2];
    #pragma unroll
    for (int i = 0; i < 4; i++) { acc[i][0] = zero; acc[i][1] = zero; }
    #pragma unroll
    for (int i = 0; i < 4; i++) {
        acc[i][0] = __builtin_amdgcn_mfma_f32_16x16x32_f16(afr[i], bfr[0], acc[i][0], 0, 0, 0);
        acc[i][1] = __builtin_amdgcn_mfma_f32_16x16x32_f16(afr[i], bfr[1], acc[i][1], 0, 0, 0);
    }
    // nt slice holds original co = 2*l15 + nt (weights pre-permuted)
    float beta[2];
    #pragma unroll
    for (int nt = 0; nt < 2; nt++) {
        int co = 2 * l15 + nt;
        float inv = g[co] * rsqrtf(vr[co] + EPSV);
        beta[nt] = bt[co] - mn[co] * inv;
    }
    #pragma unroll
    for (int i = 0; i < 4; i++) {
        int y = ty0 + 4 * w + i;
        #pragma unroll
        for (int q = 0; q < 4; q++) {
            int x = tx0 + 4 * gq + q;
            size_t ob = (((size_t)n * 64 + y) * 64 + x) * 32 + 2 * l15;
            f16 o2[2];
            o2[0] = (f16)gelu_fast(acc[i][0][q] + beta[0]);
            o2[1] = (f16)gelu_fast(acc[i][1][q] + beta[1]);
            *(uint*)(out + ob) = *(uint*)o2;
        }
    }
}

// ---------------- implicit-GEMM conv 3x3 s2 p1, NHWC f16, MFMA, reg prefetch ----------------
template<int CI, int HI, int CO>
__global__ __launch_bounds__(256) void convg_kernel(
    const f16* __restrict__ in, const f16* __restrict__ wr_,
    const float* __restrict__ g, const float* __restrict__ bt,
    const float* __restrict__ mn, const float* __restrict__ vr,
    f16* __restrict__ out)
{
    constexpr int HO = HI / 2;
    constexpr int HOB = (HO == 32) ? 5 : 4;
    constexpr int K = 9 * CI;
    __shared__ __align__(16) f16 As[64 * 40];
    __shared__ __align__(16) f16 Bs[64 * 40];
    int tid = threadIdx.x;
    int bm = blockIdx.x * 64;
    int bn = blockIdx.y * 64;
    int lrow = tid >> 2, lseg = tid & 3;
    int w = tid >> 6, lane = tid & 63;
    int wr = (w >> 1) * 32, wc = (w & 1) * 32;
    int l15 = lane & 15, l4 = lane >> 4;
    int gp = bm + lrow;
    int pn = gp >> (2 * HOB);
    int prem = gp & ((1 << (2 * HOB)) - 1);
    int oy = prem >> HOB, ox = prem & (HO - 1);

    f32x4v zero = {0.f, 0.f, 0.f, 0.f};
    f32x4v acc[2][2];
    acc[0][0] = zero; acc[0][1] = zero; acc[1][0] = zero; acc[1][1] = zero;

    auto loadTile = [&](int k0, uint4& av, uint4& bv) {
        int tap = k0 / CI;
        int cio = k0 - tap * CI;
        int ky = tap / 3, kx = tap - ky * 3;
        int iy = oy * 2 - 1 + ky, ix = ox * 2 - 1 + kx;
        av = make_uint4(0u, 0u, 0u, 0u);
        if ((unsigned)iy < (unsigned)HI && (unsigned)ix < (unsigned)HI)
            av = *(const uint4*)(in + (((size_t)(pn * HI + iy)) * HI + ix) * CI + cio + lseg * 8);
        bv = *(const uint4*)(wr_ + (size_t)(bn + lrow) * K + k0 + lseg * 8);
    };

    uint4 ra, rb;
    loadTile(0, ra, rb);
    for (int k0 = 0; k0 < K; k0 += 32) {
        __syncthreads();
        *(uint4*)(&As[lrow * 40 + lseg * 8]) = ra;
        *(uint4*)(&Bs[lrow * 40 + lseg * 8]) = rb;
        if (k0 + 32 < K) loadTile(k0 + 32, ra, rb);
        __syncthreads();
        f16x8 a0 = *(const f16x8*)(&As[(wr + l15) * 40 + l4 * 8]);
        f16x8 a1 = *(const f16x8*)(&As[(wr + 16 + l15) * 40 + l4 * 8]);
        f16x8 b0 = *(const f16x8*)(&Bs[(wc + l15) * 40 + l4 * 8]);
        f16x8 b1 = *(const f16x8*)(&Bs[(wc + 16 + l15) * 40 + l4 * 8]);
        acc[0][0] = __builtin_amdgcn_mfma_f32_16x16x32_f16(a0, b0, acc[0][0], 0, 0, 0);
        acc[0][1] = __builtin_amdgcn_mfma_f32_16x16x32_f16(a0, b1, acc[0][1], 0, 0, 0);
        acc[1][0] = __builtin_amdgcn_mfma_f32_16x16x32_f16(a1, b0, acc[1][0], 0, 0, 0);
        acc[1][1] = __builtin_amdgcn_mfma_f32_16x16x32_f16(a1, b1, acc[1][1], 0, 0, 0);
    }
    float inv[2], beta[2];
    #pragma unroll
    for (int ni = 0; ni < 2; ni++) {
        int col = bn + wc + ni * 16 + l15;
        float iv = g[col] * rsqrtf(vr[col] + EPSV);
        inv[ni] = iv; beta[ni] = bt[col] - mn[col] * iv;
    }
    #pragma unroll
    for (int mi = 0; mi < 2; mi++) {
        #pragma unroll
        for (int q = 0; q < 4; q++) {
            int pixel = bm + wr + mi * 16 + l4 * 4 + q;
            #pragma unroll
            for (int ni = 0; ni < 2; ni++) {
                int col = bn + wc + ni * 16 + l15;
                float v = acc[mi][ni][q] * inv[ni] + beta[ni];
                out[(size_t)pixel * CO + col] = (f16)gelu_fast(v);
            }
        }
    }
}

// ---------------- 4x4 avg pool NHWC f16 ----------------
__global__ __launch_bounds__(256) void poolh_kernel(
    const f16* __restrict__ in, f16* __restrict__ out, int NC)
{
    int idx = blockIdx.x * 256 + threadIdx.x;
    if (idx >= NC * 16 * 16) return;
    int cc = idx & 15; int npl = idx >> 4;
    int c0 = cc * 8;
    int n = npl >> 4; int p = npl & 15;
    int ph = p >> 2, pw = p & 3;
    const f16* base = in + (((size_t)(n * 16 + ph * 4)) * 16 + pw * 4) * 128 + c0;
    float s[8] = {};
    #pragma unroll
    for (int dy = 0; dy < 4; dy++)
        #pragma unroll
        for (int dx = 0; dx < 4; dx++) {
            f16x8 v = *(const f16x8*)(base + (dy * 16 + dx) * 128);
            #pragma unroll
            for (int u = 0; u < 8; u++) s[u] += (float)v[u];
        }
    f16* op = out + (size_t)npl * 128 + c0;
    #pragma unroll
    for (int u = 0; u < 8; u++) op[u] = (f16)(s[u] * 0.0625f);
}

// ---------------- MFMA f16 NT GEMM, 64x64 tile, BK=64, XCD-swizzled 1D grid ----------------
template<int OUTF16, int ACT, int VTRANS, int TCMAP>
__global__ __launch_bounds__(256) void gemm_k64_kernel(
    const f16* __restrict__ A, const f16* __restrict__ B,
    const float* __restrict__ bias, const float* __restrict__ res,
    void* __restrict__ Cv, f16* __restrict__ vT, int M, int N, int K, int nrow)
{
    __shared__ __align__(16) f16 As[64 * 72];
    __shared__ __align__(16) f16 Bs[64 * 72];
    int nb = gridDim.x;
    int q = nb >> 3, r = nb & 7;
    int xcd = blockIdx.x & 7, pos = blockIdx.x >> 3;
    int logical = (xcd < r ? xcd * (q + 1) : r * (q + 1) + (xcd - r) * q) + pos;
    int brow = logical % nrow, bcol = logical / nrow;
    int bm = brow * 64, bn = bcol * 64;

    int tid = threadIdx.x;
    int lrow = tid >> 2, lseg = (tid & 3) * 16;
    int w = tid >> 6, lane = tid & 63;
    int wr = (w >> 1) * 32, wc = (w & 1) * 32;
    int l15 = lane & 15, l4 = lane >> 4;
    f32x4v zero = {0.f, 0.f, 0.f, 0.f};
    f32x4v acc[2][2];
    acc[0][0] = zero; acc[0][1] = zero; acc[1][0] = zero; acc[1][1] = zero;

    int arow = bm + lrow;
    bool aok = (arow < M);
    const f16* ap = A + (size_t)arow * K + lseg;
    const f16* bp = B + (size_t)(bn + lrow) * K + lseg;

    uint4 ra0 = make_uint4(0u,0u,0u,0u), ra1 = ra0, rb0, rb1;
    if (aok) { ra0 = *(const uint4*)(ap); ra1 = *(const uint4*)(ap + 8); }
    rb0 = *(const uint4*)(bp); rb1 = *(const uint4*)(bp + 8);

    int nt = K >> 6;
    for (int t = 0; t < nt; t++) {
        __syncthreads();
        *(uint4*)(&As[lrow * 72 + lseg])     = ra0;
        *(uint4*)(&As[lrow * 72 + lseg + 8]) = ra1;
        *(uint4*)(&Bs[lrow * 72 + lseg])     = rb0;
        *(uint4*)(&Bs[lrow * 72 + lseg + 8]) = rb1;
        if (t + 1 < nt) {
            int k0 = (t + 1) << 6;
            if (aok) { ra0 = *(const uint4*)(ap + k0); ra1 = *(const uint4*)(ap + k0 + 8); }
            rb0 = *(const uint4*)(bp + k0); rb1 = *(const uint4*)(bp + k0 + 8);
        }
        __syncthreads();
        #pragma unroll
        for (int s = 0; s < 2; s++) {
            f16x8 a0 = *(const f16x8*)(&As[(wr + l15) * 72 + s * 32 + l4 * 8]);
            f16x8 a1 = *(const f16x8*)(&As[(wr + 16 + l15) * 72 + s * 32 + l4 * 8]);
            f16x8 b0 = *(const f16x8*)(&Bs[(wc + l15) * 72 + s * 32 + l4 * 8]);
            f16x8 b1 = *(const f16x8*)(&Bs[(wc + 16 + l15) * 72 + s * 32 + l4 * 8]);
            acc[0][0] = __builtin_amdgcn_mfma_f32_16x16x32_f16(a0, b0, acc[0][0], 0, 0, 0);
            acc[0][1] = __builtin_amdgcn_mfma_f32_16x16x32_f16(a0, b1, acc[0][1], 0, 0, 0);
            acc[1][0] = __builtin_amdgcn_mfma_f32_16x16x32_f16(a1, b0, acc[1][0], 0, 0, 0);
            acc[1][1] = __builtin_amdgcn_mfma_f32_16x16x32_f16(a1, b1, acc[1][1], 0, 0, 0);
        }
    }

    if (VTRANS && bn >= 768) {
        __syncthreads();
        f16* tile = As;   // [64][66]
        #pragma unroll
        for (int mi = 0; mi < 2; mi++)
            #pragma unroll
            for (int qq = 0; qq < 4; qq++) {
                int rl = wr + mi * 16 + l4 * 4 + qq;
                #pragma unroll
                for (int ni = 0; ni < 2; ni++) {
                    int dl = wc + ni * 16 + l15;
                    float v = acc[mi][ni][qq] + bias[bn + dl];
                    tile[dl * 66 + rl] = (f16)v;
                }
            }
        __syncthreads();
        int h = (bn - 768) >> 6;
        int j = tid & 63, dbase = tid >> 6;
        int trow = bm + j;
        if (trow < M) {
            int b = trow / 513;
            int jj = trow - b * 513;
            f16* vb = vT + ((size_t)(b * 6 + h) * 64) * 576 + jj;
            #pragma unroll
            for (int it = 0; it < 16; it++) {
                int d = dbase * 16 + it;
                vb[(size_t)d * 576] = tile[d * 66 + j];
            }
        }
        return;
    }
    #pragma unroll
    for (int mi = 0; mi < 2; mi++) {
        #pragma unroll
        for (int qq = 0; qq < 4; qq++) {
            int row = bm + wr + mi * 16 + l4 * 4 + qq;
            if (row >= M) continue;
            #pragma unroll
            for (int ni = 0; ni < 2; ni++) {
                int col = bn + wc + ni * 16 + l15;
                float v = acc[mi][ni][qq];
                if (bias) v += bias[col];
                if (ACT == 1) v = gelu_fast(v);
                if (res) v += res[(size_t)row * N + col];
                int orow = row;
                if (TCMAP) orow = (row & ~511) | ((row & 15) << 5) | ((row >> 4) & 31);
                if (OUTF16) ((f16*)Cv)[(size_t)orow * N + col] = (f16)v;
                else ((float*)Cv)[(size_t)orow * N + col] = v;
            }
        }
    }
}

// ---------------- MFMA f16 NT GEMM, 64x128 tile (wave 32x64), BK=64 ----------------
template<int ACT>
__global__ __launch_bounds__(256) void gemm_kn128_kernel(
    const f16* __restrict__ A, const f16* __restrict__ B,
    const float* __restrict__ bias, f16* __restrict__ C,
    int M, int N, int K, int nrow)
{
    __shared__ __align__(16) f16 As[64 * 72];
    __shared__ __align__(16) f16 Bs[128 * 72];
    int nb = gridDim.x;
    int q = nb >> 3, r = nb & 7;
    int xcd = blockIdx.x & 7, pos = blockIdx.x >> 3;
    int logical = (xcd < r ? xcd * (q + 1) : r * (q + 1) + (xcd - r) * q) + pos;
    int brow = logical % nrow, bcol = logical / nrow;
    int bm = brow * 64, bn = bcol * 128;

    int tid = threadIdx.x;
    int w = tid >> 6, lane = tid & 63;
    int wr = (w >> 1) * 32, wc = (w & 1) * 64;
    int l15 = lane & 15, l4 = lane >> 4;
    int alrow = tid >> 2, alseg = (tid & 3) * 16;
    int blrow = tid >> 1, blseg = (tid & 1) * 32;

    f32x4v zero = {0.f, 0.f, 0.f, 0.f};
    f32x4v acc[2][4];
    #pragma unroll
    for (int i = 0; i < 2; i++)
        #pragma unroll
        for (int j = 0; j < 4; j++) acc[i][j] = zero;

    int arow = bm + alrow;
    bool aok = (arow < M);
    const f16* ap = A + (size_t)arow * K + alseg;
    const f16* bp = B + (size_t)(bn + blrow) * K + blseg;

    uint4 ra0 = make_uint4(0u,0u,0u,0u), ra1 = ra0;
    uint4 rb0, rb1, rb2, rb3;
    if (aok) { ra0 = *(const uint4*)(ap); ra1 = *(const uint4*)(ap + 8); }
    rb0 = *(const uint4*)(bp);      rb1 = *(const uint4*)(bp + 8);
    rb2 = *(const uint4*)(bp + 16); rb3 = *(const uint4*)(bp + 24);

    int ntiles = K >> 6;
    for (int t = 0; t < ntiles; t++) {
        __syncthreads();
        *(uint4*)(&As[alrow * 72 + alseg])     = ra0;
        *(uint4*)(&As[alrow * 72 + alseg + 8]) = ra1;
        *(uint4*)(&Bs[blrow * 72 + blseg])      = rb0;
        *(uint4*)(&Bs[blrow * 72 + blseg + 8])  = rb1;
        *(uint4*)(&Bs[blrow * 72 + blseg + 16]) = rb2;
        *(uint4*)(&Bs[blrow * 72 + blseg + 24]) = rb3;
        if (t + 1 < ntiles) {
            int k0 = (t + 1) << 6;
            if (aok) { ra0 = *(const uint4*)(ap + k0); ra1 = *(const uint4*)(ap + k0 + 8); }
            rb0 = *(const uint4*)(bp + k0);      rb1 = *(const uint4*)(bp + k0 + 8);
            rb2 = *(const uint4*)(bp + k0 + 16); rb3 = *(const uint4*)(bp + k0 + 24);
        }
        __syncthreads();
        #pragma unroll
        for (int s = 0; s < 2; s++) {
            f16x8 a0 = *(const f16x8*)(&As[(wr + l15) * 72 + s * 32 + l4 * 8]);
            f16x8 a1 = *(const f16x8*)(&As[(wr + 16 + l15) * 72 + s * 32 + l4 * 8]);
            #pragma unroll
            for (int j = 0; j < 4; j++) {
                f16x8 bf = *(const f16x8*)(&Bs[(wc + j * 16 + l15) * 72 + s * 32 + l4 * 8]);
                acc[0][j] = __builtin_amdgcn_mfma_f32_16x16x32_f16(a0, bf, acc[0][j], 0, 0, 0);
                acc[1][j] = __builtin_amdgcn_mfma_f32_16x16x32_f16(a1, bf, acc[1][j], 0, 0, 0);
            }
        }
    }
    #pragma unroll
    for (int mi = 0; mi < 2; mi++) {
        #pragma unroll
        for (int qq = 0; qq < 4; qq++) {
            int row = bm + wr + mi * 16 + l4 * 4 + qq;
            if (row >= M) continue;
            #pragma unroll
            for (int j = 0; j < 4; j++) {
                int col = bn + wc + j * 16 + l15;
                float v = acc[mi][j][qq];
                if (bias) v += bias[col];
                if (ACT == 1) v = gelu_fast(v);
                C[(size_t)row * N + col] = (f16)v;
            }
        }
    }
}

// ---------------- depthwise temporal conv, 4 ch/thread, float4 taps -> f16 ----------------
__global__ __launch_bounds__(256) void dwconv_kernel(
    const float* __restrict__ in, const float* __restrict__ w,
    const float* __restrict__ bias, f16* __restrict__ out, int dil)
{
    int idx = blockIdx.x * 256 + threadIdx.x;
    if (idx >= 128 * 32 * 96) return;
    int dg = idx % 96; int t = (idx / 96) & 31; int s = idx / (96 * 32);
    int d = dg * 4;
    const float* ip = in + (size_t)s * 32 * 384 + d;
    float4 acc = *(const float4*)(bias + d);
    #pragma unroll
    for (int k = 0; k < 3; k++) {
        int tt = t + (k - 1) * dil;
        if ((unsigned)tt < 32u) {
            float4 v = *(const float4*)(ip + tt * 384);
            acc.x = fmaf(w[(d + 0) * 3 + k], v.x, acc.x);
            acc.y = fmaf(w[(d + 1) * 3 + k], v.y, acc.y);
            acc.z = fmaf(w[(d + 2) * 3 + k], v.z, acc.z);
            acc.w = fmaf(w[(d + 3) * 3 + k], v.w, acc.w);
        }
    }
    f16 o[4];
    o[0] = (f16)gelu_fast(acc.x); o[1] = (f16)gelu_fast(acc.y);
    o[2] = (f16)gelu_fast(acc.z); o[3] = (f16)gelu_fast(acc.w);
    *(uint2*)(out + ((size_t)(s * 32 + t) * 384 + d)) = *(uint2*)o;
}

// ---------------- LayerNorm: wave-per-row, float2 loads, f32 in -> f16 out ----------------
__global__ __launch_bounds__(256) void ln_wave_kernel(
    const float* __restrict__ in,
    const float* __restrict__ g, const float* __restrict__ b,
    f16* __restrict__ out, int rows)
{
    int w = threadIdx.x >> 6, lane = threadIdx.x & 63;
    int row = blockIdx.x * 4 + w;
    if (row >= rows) return;
    const float* ip = in + (size_t)row * 384;
    float2 x2[3]; float s = 0.f, s2 = 0.f;
    #pragma unroll
    for (int k = 0; k < 3; k++) {
        float2 v = *(const float2*)(ip + lane * 2 + 128 * k);
        x2[k] = v;
        s += v.x + v.y; s2 += v.x * v.x + v.y * v.y;
    }
    #pragma unroll
    for (int off = 1; off < 64; off <<= 1) {
        s += __shfl_xor(s, off); s2 += __shfl_xor(s2, off);
    }
    float mu = s * (1.f / 384.f);
    float var = s2 * (1.f / 384.f) - mu * mu;
    float rs = rsqrtf(var + EPSV);
    #pragma unroll
    for (int k = 0; k < 3; k++) {
        int c = lane * 2 + 128 * k;
        float2 gg = *(const float2*)(g + c);
        float2 bb = *(const float2*)(b + c);
        f16 o[2];
        o[0] = (f16)((x2[k].x - mu) * rs * gg.x + bb.x);
        o[1] = (f16)((x2[k].y - mu) * rs * gg.y + bb.y);
        *(uint*)(out + (size_t)row * 384 + c) = *(uint*)o;
    }
}

// ---------------- mixer-final LN + positional add, wave-per-row ----------------
__global__ __launch_bounds__(256) void build_x_kernel(
    const float* __restrict__ mix, const float* __restrict__ tc,
    const float* __restrict__ tg, const float* __restrict__ tb,
    const float* __restrict__ fpos, const float* __restrict__ ppos,
    float* __restrict__ x)
{
    int w = threadIdx.x >> 6, lane = threadIdx.x & 63;
    int row = blockIdx.x * 4 + w;
    if (row >= 4096) return;
    int t = row & 31; int bp = row >> 5;
    int p = bp & 15; int b = bp >> 4;
    const float* ip = mix + (size_t)row * 384;
    const float* ip2 = tc + (size_t)row * 384;
    float2 v2[3]; float s = 0.f, s2 = 0.f;
    #pragma unroll
    for (int k = 0; k < 3; k++) {
        int c = lane * 2 + 128 * k;
        float2 a = *(const float2*)(ip + c);
        float2 bb = *(const float2*)(ip2 + c);
        float2 v = make_float2(a.x + bb.x, a.y + bb.y);
        v2[k] = v;
        s += v.x + v.y; s2 += v.x * v.x + v.y * v.y;
    }
    #pragma unroll
    for (int off = 1; off < 64; off <<= 1) {
        s += __shfl_xor(s, off); s2 += __shfl_xor(s2, off);
    }
    float mu = s * (1.f / 384.f);
    float var = s2 * (1.f / 384.f) - mu * mu;
    float rs = rsqrtf(var + EPSV);
    size_t xbase = ((size_t)b * 513 + 1 + t * 16 + p) * 384;
    #pragma unroll
    for (int k = 0; k < 3; k++) {
        int c = lane * 2 + 128 * k;
        float2 gg = *(const float2*)(tg + c);
        float2 bb = *(const float2*)(tb + c);
        float2 fp = *(const float2*)(fpos + t * 384 + c);
        float2 pp = *(const float2*)(ppos + p * 384 + c);
        float2 y;
        y.x = (v2[k].x - mu) * rs * gg.x + bb.x + fp.x + pp.x;
        y.y = (v2[k].y - mu) * rs * gg.y + bb.y + fp.y + pp.y;
        *(float2*)(x + xbase + c) = y;
    }
}

__global__ __launch_bounds__(256) void cls_kernel(
    const float* __restrict__ ct, const float* __restrict__ cp, float* __restrict__ x)
{
    int idx = blockIdx.x * 256 + threadIdx.x;
    if (idx >= 8 * 384) return;
    int c = idx % 384; int b = idx / 384;
    x[(size_t)b * 513 * 384 + c] = ct[c] + cp[c];
}

// ---------------- flash attention, SPLITS-way j-split + K/V register prefetch ----------------
__global__ __launch_bounds__(256) void fattn_split_kernel(
    const f16* __restrict__ qkv, const f16* __restrict__ vT,
    f16* __restrict__ Op, float* __restrict__ ml)
{
    __shared__ __align__(16) f16 Pl[4][16][72];
    int qt = blockIdx.x;
    int bh = blockIdx.y; int h = bh % 6; int b = bh / 6;
    int third = blockIdx.z;
    int tid = threadIdx.x;
    int w = tid >> 6, lane = tid & 63;
    int l15 = lane & 15, g = lane >> 4;
    int q0w = qt * 64 + w * 16;
    if (q0w > 512) return;
    const size_t RS = 1152;
    const f16* qbase = qkv + (size_t)b * 513 * RS + h * 64;
    const f16* kbase = qbase + 384;
    const f16* vtb = vT + (size_t)bh * 64 * 576;

    f16x8 qf[2];
    {
        int qrow = q0w + l15; if (qrow > 512) qrow = 512;
        const f16* qp = qbase + (size_t)qrow * RS + g * 8;
        qf[0] = *(const f16x8*)(qp);
        qf[1] = *(const f16x8*)(qp + 32);
    }

    f32x4v zero = {0.f, 0.f, 0.f, 0.f};
    f32x4v O[4]; float m[4], l[4];
    #pragma unroll
    for (int i = 0; i < 4; i++) { O[i] = zero; m[i] = -INFINITY; l[i] = 0.f; }

    int jt0 = 0;
    if (q0w > 0) { int fmin = (q0w - 1) >> 4; jt0 = (fmin * 16 + 1) >> 6; }

    int jrow[4];
    #pragma unroll
    for (int jf = 0; jf < 4; jf++) jrow[jf] = jf * 16 + l15;

    auto loadK = [&](int j0, f16x8* kr) {
        #pragma unroll
        for (int s = 0; s < 2; s++)
            #pragma unroll
            for (int jf = 0; jf < 4; jf++) {
                int j = j0 + jrow[jf]; if (j > 512) j = 512;
                kr[s * 4 + jf] = *(const f16x8*)(kbase + (size_t)j * RS + s * 32 + g * 8);
            }
    };

    int jt = jt0 + third;
    f16x8 kreg[8];
    if (jt < 9) loadK(jt * 64, kreg);

    for (; jt < 9; jt += SPLITS) {
        int j0 = jt * 64;
        f16x8 vreg[8];
        #pragma unroll
        for (int s = 0; s < 2; s++)
            #pragma unroll
            for (int df = 0; df < 4; df++)
                vreg[s * 4 + df] = *(const f16x8*)(vtb + (size_t)(df * 16 + l15) * 576 + j0 + s * 32 + g * 8);
        f32x4v S[4];
        #pragma unroll
        for (int jf = 0; jf < 4; jf++) S[jf] = zero;
        #pragma unroll
        for (int s = 0; s < 2; s++)
            #pragma unroll
            for (int jf = 0; jf < 4; jf++)
                S[jf] = __builtin_amdgcn_mfma_f32_16x16x32_f16(qf[s], kreg[s * 4 + jf], S[jf], 0, 0, 0);
        f16x8 knext[8];
        if (jt + SPLITS < 9) loadK((jt + SPLITS) * 64, knext);
        float pj[4][4];
        #pragma unroll
        for (int r = 0; r < 4; r++) {
            int qi = q0w + 4 * g + r;
            int fi = (qi == 0) ? -1 : ((qi - 1) >> 4);
            float mx = -INFINITY;
            #pragma unroll
            for (int jf = 0; jf < 4; jf++) {
                int j = j0 + jrow[jf];
                bool valid = (qi < 513) && (j < 513) &&
                             !((qi != 0) && ((j == 0) || (((j - 1) >> 4) < fi)));
                float sv = valid ? S[jf][r] * 0.125f : -INFINITY;
                pj[jf][r] = sv;
                mx = fmaxf(mx, sv);
            }
            mx = fmaxf(mx, __shfl_xor(mx, 1));
            mx = fmaxf(mx, __shfl_xor(mx, 2));
            mx = fmaxf(mx, __shfl_xor(mx, 4));
            mx = fmaxf(mx, __shfl_xor(mx, 8));
            float mn = fmaxf(m[r], mx);
            float alpha = (m[r] == -INFINITY) ? 0.f : __expf(m[r] - mn);
            float ls = 0.f;
            #pragma unroll
            for (int jf = 0; jf < 4; jf++) {
                float p = (pj[jf][r] == -INFINITY) ? 0.f : __expf(pj[jf][r] - mn);
                pj[jf][r] = p; ls += p;
            }
            ls += __shfl_xor(ls, 1); ls += __shfl_xor(ls, 2);
            ls += __shfl_xor(ls, 4); ls += __shfl_xor(ls, 8);
            l[r] = alpha * l[r] + ls;
            m[r] = mn;
            #pragma unroll
            for (int df = 0; df < 4; df++) O[df][r] *= alpha;
        }
        #pragma unroll
        for (int jf = 0; jf < 4; jf++)
            #pragma unroll
            for (int r = 0; r < 4; r++)
                Pl[w][4 * g + r][jf * 16 + l15] = (f16)pj[jf][r];
        #pragma unroll
        for (int s = 0; s < 2; s++) {
            f16x8 pf = *(const f16x8*)(&Pl[w][l15][s * 32 + g * 8]);
            #pragma unroll
            for (int df = 0; df < 4; df++)
                O[df] = __builtin_amdgcn_mfma_f32_16x16x32_f16(pf, vreg[s * 4 + df], O[df], 0, 0, 0);
        }
        #pragma unroll
        for (int i = 0; i < 8; i++) kreg[i] = knext[i];
    }

    int rowbase = third * 24624 + bh * 513;
    #pragma unroll
    for (int r = 0; r < 4; r++) {
        int qi = q0w + 4 * g + r;
        if (qi > 512) continue;
        size_t ro = (size_t)(rowbase + qi);
        #pragma unroll
        for (int df = 0; df < 4; df++)
            Op[ro * 64 + df * 16 + l15] = (f16)O[df][r];
        if (l15 == 0) {
            ml[ro * 2 + 0] = m[r];
            ml[ro * 2 + 1] = l[r];
        }
    }
}

// ---------------- combine SPLITS attention partials -> ob f16 ----------------
__global__ __launch_bounds__(256) void attn_combine_kernel(
    const f16* __restrict__ Op, const float* __restrict__ ml,
    f16* __restrict__ ob)
{
    int row = blockIdx.x * 4 + (threadIdx.x >> 6);
    if (row >= 24624) return;
    int lane = threadIdx.x & 63;
    int bh = row / 513, qi = row - bh * 513;
    int b = bh / 6, h = bh - b * 6;
    float mv[SPLITS], lv[SPLITS], mm = -INFINITY;
    #pragma unroll
    for (int s = 0; s < SPLITS; s++) {
        mv[s] = ml[((size_t)s * 24624 + row) * 2];
        lv[s] = ml[((size_t)s * 24624 + row) * 2 + 1];
        mm = fmaxf(mm, mv[s]);
    }
    float onum = 0.f, lden = 0.f;
    #pragma unroll
    for (int s = 0; s < SPLITS; s++) {
        float a = (mv[s] == -INFINITY) ? 0.f : __expf(mv[s] - mm);
        lden += lv[s] * a;
        onum += (float)Op[((size_t)s * 24624 + row) * 64 + lane] * a;
    }
    ob[((size_t)(b * 513 + qi)) * 384 + h * 64 + lane] = (f16)(onum / lden);
}

// ---------------- head ----------------
__global__ __launch_bounds__(384) void head_kernel(
    const float* __restrict__ x, const float* __restrict__ lg, const float* __restrict__ lb,
    const float* __restrict__ w1, const float* __restrict__ b1,
    const float* __restrict__ w2, const float* __restrict__ b2,
    float* __restrict__ out)
{
    int b = blockIdx.x; int t = threadIdx.x;
    __shared__ float hs[384], h1[384];
    __shared__ float rs[6], rs2[6];
    const float* xp = x + (size_t)b * 513 * 384;
    float v = xp[t];
    float s = v, s2 = v * v;
    #pragma unroll
    for (int off = 32; off >= 1; off >>= 1) {
        s += __shfl_down(s, off); s2 += __shfl_down(s2, off);
    }
    if ((t & 63) == 0) { rs[t >> 6] = s; rs2[t >> 6] = s2; }
    __syncthreads();
    float S = 0.f, S2 = 0.f;
    #pragma unroll
    for (int i = 0; i < 6; i++) { S += rs[i]; S2 += rs2[i]; }
    float mu = S * (1.f / 384.f);
    float var = S2 * (1.f / 384.f) - mu * mu;
    float rstd = rsqrtf(var + EPSV);
    hs[t] = (v - mu) * rstd * lg[t] + lb[t];
    __syncthreads();
    const float* wr = w1 + (size_t)t * 384;
    float acc = b1[t];
    for (int c = 0; c < 384; c += 4) {
        float4 w4 = *reinterpret_cast<const float4*>(wr + c);
        acc += w4.x * hs[c] + w4.y * hs[c + 1] + w4.z * hs[c + 2] + w4.w * hs[c + 3];
    }
    h1[t] = gelu_f(acc);
    __syncthreads();
    float p0 = h1[t] * w2[t], p1 = h1[t] * w2[384 + t];
    #pragma unroll
    for (int off = 32; off >= 1; off >>= 1) {
        p0 += __shfl_down(p0, off); p1 += __shfl_down(p1, off);
    }
    if ((t & 63) == 0) { rs[t >> 6] = p0; rs2[t >> 6] = p1; }
    __syncthreads();
    if (t == 0) {
        float a0 = b2[0], a1 = b2[1];
        #pragma unroll
        for (int i = 0; i < 6; i++) { a0 += rs[i]; a1 += rs2[i]; }
        out[b * 2 + 0] = 1.f / (1.f + expf(-a0));
        out[b * 2 + 1] = 1.f / (1.f + expf(-a1));
    }
}

static inline int cdiv(int a, int b) { return (a + b - 1) / b; }

extern "C" void kernel_launch(void* const* d_in, const int* in_sizes, int n_in,
                              void* d_out, int out_size, void* d_ws, size_t ws_size,
                              hipStream_t stream)
{
    const float* frames  = (const float*)d_in[0];
    const float* conv1_w = (const float*)d_in[1];
    const float* bn1_g = (const float*)d_in[2]; const float* bn1_b = (const float*)d_in[3];
    const float* bn1_m = (const float*)d_in[4]; const float* bn1_v = (const float*)d_in[5];
    const float* conv2_w = (const float*)d_in[6];
    const float* bn2_g = (const float*)d_in[7]; const float* bn2_b = (const float*)d_in[8];
    const float* bn2_m = (const float*)d_in[9]; const float* bn2_v = (const float*)d_in[10];
    const float* conv3_w = (const float*)d_in[11];
    const float* bn3_g = (const float*)d_in[12]; const float* bn3_b = (const float*)d_in[13];
    const float* bn3_m = (const float*)d_in[14]; const float* bn3_v = (const float*)d_in[15];
    const float* proj_w = (const float*)d_in[16];
    const float* dw_w = (const float*)d_in[17]; const float* dw_b = (const float*)d_in[18];
    const float* pw_w = (const float*)d_in[19]; const float* pw_b = (const float*)d_in[20];
    const float* tnorm_g = (const float*)d_in[21]; const float* tnorm_b = (const float*)d_in[22];
    const float* frame_pos = (const float*)d_in[23];
    const float* patch_pos = (const float*)d_in[24];
    const float* cls_token = (const float*)d_in[25];
    const float* cls_pos = (const float*)d_in[26];
    const float* qkv_w = (const float*)d_in[27]; const float* qkv_b = (const float*)d_in[28];
    const float* out_w = (const float*)d_in[29]; const float* out_b = (const float*)d_in[30];
    const float* ln1_g = (const float*)d_in[31]; const float* ln1_b = (const float*)d_in[32];
    const float* ln2_g = (const float*)d_in[33]; const float* ln2_b = (const float*)d_in[34];
    const float* ffn_w1 = (const float*)d_in[35]; const float* ffn_b1 = (const float*)d_in[36];
    const float* ffn_w2 = (const float*)d_in[37]; const float* ffn_b2 = (const float*)d_in[38];
    const float* head_ln_g = (const float*)d_in[39]; const float* head_ln_b = (const float*)d_in[40];
    const float* head_w1 = (const float*)d_in[41]; const float* head_b1 = (const float*)d_in[42];
    const float* head_w2 = (const float*)d_in[43]; const float* head_b2 = (const float*)d_in[44];
    (void)in_sizes; (void)n_in; (void)out_size; (void)ws_size;

    char* base = (char*)d_ws;
    size_t off = 0;
    auto alloc = [&](size_t bytes) { void* p = base + off; off = (off + bytes + 255) & ~(size_t)255; return p; };

    // persistent region
    f16* wtotal = (f16*)alloc((size_t)10960896 * 2);
    f16* projw16 = wtotal;
    f16* pw16    = wtotal + 49152;
    f16* qkvw16  = wtotal + 344064;
    f16* outw16  = wtotal + 2998272;
    f16* f1w16   = wtotal + 3883008;
    f16* f2w16   = wtotal + 7421952;
    f16* c1wB    = (f16*)alloc(1024 * 2);
    f16* c2w16   = (f16*)alloc((size_t)64 * 288 * 2);
    f16* c3w16   = (f16*)alloc((size_t)128 * 576 * 2);
    f16* pooled  = (f16*)alloc((size_t)4096 * 128 * 2);
    float* tc    = (float*)alloc((size_t)4096 * 384 * 4);

    // union region: stem scratch vs mixer/transformer scratch
    size_t ustart = off;
    f16* c1h = (f16*)alloc((size_t)256 * 64 * 64 * 32 * 2);
    f16* c2h = (f16*)alloc((size_t)256 * 32 * 32 * 64 * 2);
    f16* c3h = (f16*)alloc((size_t)256 * 16 * 16 * 128 * 2);
    size_t uend_stem = off;
    off = ustart;
    float* mA = (float*)alloc((size_t)4096 * 384 * 4);
    float* mB = (float*)alloc((size_t)4096 * 384 * 4);
    f16*   mh = (f16*)alloc((size_t)4096 * 384 * 2);
    float* xb   = (float*)alloc((size_t)8 * 513 * 384 * 4);
    f16*   hb   = (f16*)alloc((size_t)8 * 513 * 384 * 2);
    f16*   qkvb = (f16*)alloc((size_t)8 * 513 * 1152 * 2);
    f16*   vTb  = (f16*)alloc((size_t)48 * 64 * 576 * 2);
    f16*   ob   = (f16*)alloc((size_t)8 * 513 * 384 * 2);
    f16*   ffb  = (f16*)alloc((size_t)8 * 513 * 1536 * 2);
    f16*   Opart = (f16*)alloc((size_t)SPLITS * 24624 * 64 * 2);
    float* mlpart = (float*)alloc((size_t)SPLITS * 24624 * 2 * 4);
    if (off < uend_stem) off = uend_stem;

    // ---------- one prep dispatch ----------
    prep_all_kernel<<<4096, 256, 0, stream>>>(
        proj_w, pw_w, qkv_w, out_w, ffn_w1, ffn_w2, wtotal,
        conv1_w, bn1_g, bn1_v, c1wB, conv2_w, c2w16, conv3_w, c3w16);

    // ---------- conv stem, full 256-frame batch ----------
    conv1_mfma_kernel<<<256 * 16, 256, 0, stream>>>(
        frames, c1wB, bn1_b, bn1_m, bn1_g, bn1_v, c1h);
    convg_kernel<32, 64, 64><<<dim3(4096, 1), 256, 0, stream>>>(
        c1h, c2w16, bn2_g, bn2_b, bn2_m, bn2_v, c2h);
    convg_kernel<64, 32, 128><<<dim3(1024, 2), 256, 0, stream>>>(
        c2h, c3w16, bn3_g, bn3_b, bn3_m, bn3_v, c3h);
    poolh_kernel<<<256, 256, 0, stream>>>(c3h, pooled, 256);
    // proj with TCMAP epilogue: writes directly into tc layout (b*16+p, t, d)
    gemm_k64_kernel<0, 0, 0, 1><<<384, 256, 0, stream>>>(
        pooled, projw16, nullptr, nullptr, tc, nullptr, 4096, 384, 128, 64);

    // ---------- temporal mixer (iter0 reads tc directly) ----------
    dwconv_kernel<<<cdiv(128 * 32 * 96, 256), 256, 0, stream>>>(
        tc, dw_w, dw_b, mh, 1);
    gemm_k64_kernel<0, 0, 0, 0><<<384, 256, 0, stream>>>(
        mh, pw16, pw_b, tc, mA, nullptr, 4096, 384, 384, 64);
    dwconv_kernel<<<cdiv(128 * 32 * 96, 256), 256, 0, stream>>>(
        mA, dw_w + 384 * 3, dw_b + 384, mh, 2);
    gemm_k64_kernel<0, 0, 0, 0><<<384, 256, 0, stream>>>(
        mh, pw16 + 384 * 384, pw_b + 384, mA, mB, nullptr, 4096, 384, 384, 64);

    // ---------- build transformer input x ----------
    build_x_kernel<<<1024, 256, 0, stream>>>(
        mB, tc, tnorm_g, tnorm_b, frame_pos, patch_pos, xb);
    cls_kernel<<<cdiv(8 * 384, 256), 256, 0, stream>>>(cls_token, cls_pos, xb);

    // ---------- transformer ----------
    const int M = 8 * 513;        // 4104
    const int NR = cdiv(M, 64);   // 65
    for (int l = 0; l < 6; l++) {
        ln_wave_kernel<<<cdiv(M, 4), 256, 0, stream>>>(xb,
            ln1_g + (size_t)l * 384, ln1_b + (size_t)l * 384, hb, M);
        gemm_k64_kernel<1, 0, 1, 0><<<NR * 18, 256, 0, stream>>>(
            hb, qkvw16 + (size_t)l * 1152 * 384, qkv_b + (size_t)l * 1152,
            nullptr, qkvb, vTb, M, 1152, 384, NR);
        fattn_split_kernel<<<dim3(9, 48, SPLITS), 256, 0, stream>>>(qkvb, vTb, Opart, mlpart);
        attn_combine_kernel<<<cdiv(24624, 4), 256, 0, stream>>>(Opart, mlpart, ob);
        gemm_k64_kernel<0, 0, 0, 0><<<NR * 6, 256, 0, stream>>>(
            ob, outw16 + (size_t)l * 384 * 384, out_b + (size_t)l * 384,
            xb, xb, nullptr, M, 384, 384, NR);
        ln_wave_kernel<<<cdiv(M, 4), 256, 0, stream>>>(xb,
            ln2_g + (size_t)l * 384, ln2_b + (size_t)l * 384, hb, M);
        gemm_kn128_kernel<1><<<NR * 12, 256, 0, stream>>>(
            hb, f1w16 + (size_t)l * 1536 * 384, ffn_b1 + (size_t)l * 1536,
            ffb, M, 1536, 384, NR);
        gemm_k64_kernel<0, 0, 0, 0><<<NR * 6, 256, 0, stream>>>(
            ffb, f2w16 + (size_t)l * 384 * 1536, ffn_b2 + (size_t)l * 384,
            xb, xb, nullptr, M, 384, 1536, NR);
    }

    // ---------- head ----------
    head_kernel<<<8, 384, 0, stream>>>(
        xb, head_ln_g, head_ln_b, head_w1, head_b1, head_w2, head_b2, (float*)d_out);
}